// Round 1
// baseline (1821.643 us; speedup 1.0000x reference)
//
#include <hip/hip_runtime.h>

#define B_    256
#define G_    200
#define S_    100
#define NODE_ 200
#define E_    128
#define H_    8
#define Kd_   16
#define M_    300   // NODE + S
#define GT_   25    // g-tile per block
#define SCST_ 308   // score row stride (floats), 308*4 % 16 == 0 -> aligned b128
#define CLIP_ 10.0f

// ---------------- K1: qbase[b][c] = graph[b][:] @ Wq[:128][c] ----------------
__global__ __launch_bounds__(128) void qbase_kernel(
    const float* __restrict__ graph, const float* __restrict__ Wq,
    float* __restrict__ qbase)
{
    const int b = blockIdx.x;
    const int c = threadIdx.x;
    __shared__ float gs[E_];
    gs[c] = graph[b*E_ + c];
    __syncthreads();
    float acc = 0.f;
    #pragma unroll 8
    for (int e = 0; e < E_; ++e) acc += gs[e] * Wq[e*E_ + c];
    qbase[b*E_ + c] = acc;
}

// ---------------- K2: fused projections ----------------
// kT[b][c][m]  = (enc[b] @ Wk)^T   (c in 0..127, m in 0..299)
// v  [b][m][c] =  enc[b] @ Wv
// shkT[b][c][n]= (enc[b][:200] @ Wk_logit)^T
__global__ __launch_bounds__(256) void proj_kernel(
    const float* __restrict__ X,
    const float* __restrict__ Wk, const float* __restrict__ Wv,
    const float* __restrict__ Wl,
    float* __restrict__ kT, float* __restrict__ vbuf, float* __restrict__ shkT)
{
    const int b  = blockIdx.y;
    const int m0 = blockIdx.x * 32;
    const int t  = threadIdx.x;
    __shared__ float Xs[32*128];
    __shared__ float Ws[32*128];

    #pragma unroll
    for (int i = 0; i < 4; ++i) {
        const int f4  = t + 256*i;
        const int row = f4 >> 5;
        const int c4  = (f4 & 31) << 2;
        const int m   = m0 + row;
        float4 val = make_float4(0.f, 0.f, 0.f, 0.f);
        if (m < M_) val = *(const float4*)&X[(b*M_ + m)*E_ + c4];
        *(float4*)&Xs[row*128 + c4] = val;
    }
    const int rg = t >> 5;      // 0..7 -> 4 rows each
    const int cg = t & 31;      // 0..31 -> 4 cols each
    const int mb = m0 + rg*4;

    for (int p = 0; p < 3; ++p) {
        if (p == 2 && m0 >= NODE_) break;   // uniform: whole tile past shk rows
        const float* W = (p == 0) ? Wk : ((p == 1) ? Wv : Wl);
        float acc[4][4];
        #pragma unroll
        for (int i = 0; i < 4; ++i) {
            #pragma unroll
            for (int j = 0; j < 4; ++j) acc[i][j] = 0.f;
        }
        for (int kc = 0; kc < 4; ++kc) {
            __syncthreads();
            #pragma unroll
            for (int i = 0; i < 4; ++i) {
                const int f4  = t + 256*i;
                const int row = f4 >> 5;
                const int c4  = (f4 & 31) << 2;
                *(float4*)&Ws[row*128 + c4] = *(const float4*)&W[(kc*32 + row)*E_ + c4];
            }
            __syncthreads();
            #pragma unroll
            for (int kk = 0; kk < 32; ++kk) {
                const float4 w4 = *(const float4*)&Ws[kk*128 + cg*4];
                const float x0 = Xs[(rg*4+0)*128 + kc*32 + kk];
                const float x1 = Xs[(rg*4+1)*128 + kc*32 + kk];
                const float x2 = Xs[(rg*4+2)*128 + kc*32 + kk];
                const float x3 = Xs[(rg*4+3)*128 + kc*32 + kk];
                acc[0][0] += x0*w4.x; acc[0][1] += x0*w4.y; acc[0][2] += x0*w4.z; acc[0][3] += x0*w4.w;
                acc[1][0] += x1*w4.x; acc[1][1] += x1*w4.y; acc[1][2] += x1*w4.z; acc[1][3] += x1*w4.w;
                acc[2][0] += x2*w4.x; acc[2][1] += x2*w4.y; acc[2][2] += x2*w4.z; acc[2][3] += x2*w4.w;
                acc[3][0] += x3*w4.x; acc[3][1] += x3*w4.y; acc[3][2] += x3*w4.z; acc[3][3] += x3*w4.w;
            }
        }
        if (p == 0) {
            if (mb < M_) {              // 4-row groups never straddle 300 (300%4==0)
                #pragma unroll
                for (int j = 0; j < 4; ++j) {
                    float4 o = make_float4(acc[0][j], acc[1][j], acc[2][j], acc[3][j]);
                    *(float4*)&kT[(b*E_ + cg*4 + j)*M_ + mb] = o;
                }
            }
        } else if (p == 1) {
            #pragma unroll
            for (int i = 0; i < 4; ++i) {
                const int m = mb + i;
                if (m < M_) {
                    float4 o = make_float4(acc[i][0], acc[i][1], acc[i][2], acc[i][3]);
                    *(float4*)&vbuf[(b*M_ + m)*E_ + cg*4] = o;
                }
            }
        } else {
            if (mb < NODE_) {           // 200%4==0 -> group aligned
                #pragma unroll
                for (int j = 0; j < 4; ++j) {
                    float4 o = make_float4(acc[0][j], acc[1][j], acc[2][j], acc[3][j]);
                    *(float4*)&shkT[(b*E_ + cg*4 + j)*NODE_ + mb] = o;
                }
            }
        }
    }
}

// ---------------- K3: fused attention + Wc + logits + softmax ----------------
__global__ __launch_bounds__(256) void attn_kernel(
    const float* __restrict__ capacity,
    const float* __restrict__ sols_mask,
    const float* __restrict__ ninf_mask,
    const float* __restrict__ Wq,
    const float* __restrict__ Wc,
    const float* __restrict__ bc,
    const float* __restrict__ kT,
    const float* __restrict__ vbuf,
    const float* __restrict__ shkT,
    const float* __restrict__ qbase,
    float* __restrict__ out)
{
    const int gt = blockIdx.x;           // 0..7
    const int b  = blockIdx.y;
    const int g0 = gt * GT_;
    const int t  = threadIdx.x;

    __shared__ float q_lds[GT_*E_];      // 12.8 KB ; reused as mh after h-loop
    __shared__ float sc_lds[GT_*SCST_];  // 30.8 KB ; scores/weights, then logits
    __shared__ float out_lds[GT_*E_];    // 12.8 KB ; attention output (all heads)
    __shared__ float red_lds[GT_*2];     // 1/denominators per (g, segment)

    // ---- stage q[g][c] = qbase[b][c] + cap[b][g0+g] * Wq[128][c] ----
    {
        const int c = t & 127, gp = t >> 7;
        const float qv  = qbase[b*E_ + c];
        const float wql = Wq[E_*E_ + c];     // last row of (129,128) Wq
        for (int g = gp; g < GT_; g += 2) {
            const float cap = capacity[b*G_ + g0 + g];
            q_lds[g*E_ + c] = qv + cap * wql;
        }
    }
    // ---- masks for this thread's key m=t, kept in registers across heads ----
    float mreg[GT_];
    {
        const int m1 = t;
        #pragma unroll
        for (int g = 0; g < GT_; ++g) {
            const int gg = g0 + g;
            mreg[g] = (m1 < NODE_)
                ? ninf_mask[(b*G_ + gg)*NODE_ + m1]
                : sols_mask[(b*G_ + gg)*S_ + (m1 - NODE_)];
        }
    }
    __syncthreads();

    const float* kTb = kT   + b*E_*M_;
    const float* vb  = vbuf + b*M_*E_;

    for (int h = 0; h < H_; ++h) {
        // ---- phase a: scores (thread-per-key m) ----
        {
            const int m = t;
            float kv[Kd_];
            #pragma unroll
            for (int kk = 0; kk < Kd_; ++kk) kv[kk] = kTb[(h*Kd_ + kk)*M_ + m];
            #pragma unroll
            for (int g = 0; g < GT_; ++g) {
                const float4* qp = (const float4*)&q_lds[g*E_ + h*Kd_];
                const float4 q0 = qp[0], q1 = qp[1], q2 = qp[2], q3 = qp[3];
                float s;
                s  = q0.x*kv[0]  + q0.y*kv[1]  + q0.z*kv[2]  + q0.w*kv[3];
                s += q1.x*kv[4]  + q1.y*kv[5]  + q1.z*kv[6]  + q1.w*kv[7];
                s += q2.x*kv[8]  + q2.y*kv[9]  + q2.z*kv[10] + q2.w*kv[11];
                s += q3.x*kv[12] + q3.y*kv[13] + q3.z*kv[14] + q3.w*kv[15];
                sc_lds[g*SCST_ + m] = s*0.25f + mreg[g];
            }
            if (t < M_ - 256) {          // tail keys 256..299
                const int m2 = 256 + t;
                float kv2[Kd_];
                #pragma unroll
                for (int kk = 0; kk < Kd_; ++kk) kv2[kk] = kTb[(h*Kd_ + kk)*M_ + m2];
                #pragma unroll
                for (int g = 0; g < GT_; ++g) {
                    const float4* qp = (const float4*)&q_lds[g*E_ + h*Kd_];
                    const float4 q0 = qp[0], q1 = qp[1], q2 = qp[2], q3 = qp[3];
                    float s;
                    s  = q0.x*kv2[0]  + q0.y*kv2[1]  + q0.z*kv2[2]  + q0.w*kv2[3];
                    s += q1.x*kv2[4]  + q1.y*kv2[5]  + q1.z*kv2[6]  + q1.w*kv2[7];
                    s += q2.x*kv2[8]  + q2.y*kv2[9]  + q2.z*kv2[10] + q2.w*kv2[11];
                    s += q3.x*kv2[12] + q3.y*kv2[13] + q3.z*kv2[14] + q3.w*kv2[15];
                    const float msk = sols_mask[(b*G_ + g0 + g)*S_ + (m2 - NODE_)];
                    sc_lds[g*SCST_ + m2] = s*0.25f + msk;
                }
            }
        }
        __syncthreads();
        // ---- phase b: two-segment softmax (keep unnormalized exp in LDS) ----
        {
            const int g = t >> 3, part = t & 7;
            if (g < GT_) {
                float mx0 = -3.0e38f, mx1 = -3.0e38f;
                for (int m = part; m < M_; m += 8) {
                    const float s = sc_lds[g*SCST_ + m];
                    if (m < NODE_) mx0 = fmaxf(mx0, s);
                    else           mx1 = fmaxf(mx1, s);
                }
                #pragma unroll
                for (int off = 1; off < 8; off <<= 1) {
                    mx0 = fmaxf(mx0, __shfl_xor(mx0, off));
                    mx1 = fmaxf(mx1, __shfl_xor(mx1, off));
                }
                float sum0 = 0.f, sum1 = 0.f;
                for (int m = part; m < M_; m += 8) {
                    const float s = sc_lds[g*SCST_ + m];
                    const float e = __expf(s - ((m < NODE_) ? mx0 : mx1));
                    sc_lds[g*SCST_ + m] = e;
                    if (m < NODE_) sum0 += e;
                    else           sum1 += e;
                }
                #pragma unroll
                for (int off = 1; off < 8; off <<= 1) {
                    sum0 += __shfl_xor(sum0, off);
                    sum1 += __shfl_xor(sum1, off);
                }
                if (part == 0) {
                    red_lds[g*2 + 0] = 1.f / sum0;
                    red_lds[g*2 + 1] = 1.f / sum1;
                }
            }
        }
        __syncthreads();
        // ---- phase c: PV (thread = (k, g-slot)), fold 1/denoms here ----
        {
            const int k  = t & 15;
            const int gs = t >> 4;
            const float* vcol = vb + h*Kd_ + k;
            #pragma unroll
            for (int gp2 = 0; gp2 < 2; ++gp2) {
                const int g = gs + gp2*16;
                if (g < GT_) {
                    float accn = 0.f, accs = 0.f;
                    #pragma unroll 5
                    for (int m = 0; m < NODE_; m += 4) {
                        const float4 w4 = *(const float4*)&sc_lds[g*SCST_ + m];
                        accn += w4.x * vcol[(m+0)*E_];
                        accn += w4.y * vcol[(m+1)*E_];
                        accn += w4.z * vcol[(m+2)*E_];
                        accn += w4.w * vcol[(m+3)*E_];
                    }
                    #pragma unroll 5
                    for (int m = NODE_; m < M_; m += 4) {
                        const float4 w4 = *(const float4*)&sc_lds[g*SCST_ + m];
                        accs += w4.x * vcol[(m+0)*E_];
                        accs += w4.y * vcol[(m+1)*E_];
                        accs += w4.z * vcol[(m+2)*E_];
                        accs += w4.w * vcol[(m+3)*E_];
                    }
                    out_lds[g*E_ + h*Kd_ + k] = accn*red_lds[g*2+0] + accs*red_lds[g*2+1];
                }
            }
        }
        __syncthreads();
    }

    // ---- mh = out @ Wc + bc  (lane pairs split K, shuffle-combine) ----
    {
        const int part = t & 1;
        const int j    = t >> 1;
        const float bcj = bc[j];
        const int c0 = part * 64;
        for (int g = 0; g < GT_; ++g) {
            float acc = 0.f;
            const float* og = &out_lds[g*E_ + c0];
            const float* wc = &Wc[c0*E_ + j];
            #pragma unroll 8
            for (int c = 0; c < 64; ++c) acc += og[c] * wc[c*E_];
            acc += __shfl_xor(acc, 1);
            if (part == 0) q_lds[g*E_ + j] = acc + bcj;   // q_lds now holds mh
        }
    }
    __syncthreads();

    // ---- final logits: 10*tanh(mh.shk/sqrt(E)) + mask ----
    {
        const int part = t & 1;
        const int ns   = t >> 1;           // 0..127
        const int n2   = ns + 128;
        const int n2c  = (n2 < NODE_) ? n2 : 0;
        const float rE = 0.08838834764831845f;  // 1/sqrt(128)
        const float* shb = shkT + b*E_*NODE_;
        const int c0 = part * 64;
        for (int g = 0; g < GT_; ++g) {
            float acc1 = 0.f, acc2 = 0.f;
            const float* mhg = &q_lds[g*E_ + c0];
            const float* s1p = shb + c0*NODE_ + ns;
            const float* s2p = shb + c0*NODE_ + n2c;
            #pragma unroll 4
            for (int c = 0; c < 64; ++c) {
                const float mv = mhg[c];
                acc1 += mv * s1p[c*NODE_];
                acc2 += mv * s2p[c*NODE_];
            }
            acc1 += __shfl_xor(acc1, 1);
            acc2 += __shfl_xor(acc2, 1);
            const int n = part ? n2 : ns;
            if (n < NODE_) {
                const float a  = (part ? acc2 : acc1) * rE;
                const float ex = __expf(2.f * a);          // saturates -> tanh = +-1
                const float th = 1.f - 2.f / (ex + 1.f);
                const float s2 = CLIP_ * th + ninf_mask[(b*G_ + g0 + g)*NODE_ + n];
                sc_lds[g*SCST_ + n] = s2;
            }
        }
    }
    __syncthreads();

    // ---- final row softmax over n + store ----
    {
        const int g = t >> 3, part = t & 7;
        if (g < GT_) {
            float mx = -3.0e38f;
            for (int n = part; n < NODE_; n += 8)
                mx = fmaxf(mx, sc_lds[g*SCST_ + n]);
            #pragma unroll
            for (int off = 1; off < 8; off <<= 1)
                mx = fmaxf(mx, __shfl_xor(mx, off));
            float sum = 0.f;
            for (int n = part; n < NODE_; n += 8) {
                const float e = __expf(sc_lds[g*SCST_ + n] - mx);
                sc_lds[g*SCST_ + n] = e;
                sum += e;
            }
            #pragma unroll
            for (int off = 1; off < 8; off <<= 1)
                sum += __shfl_xor(sum, off);
            const float rs = 1.f / sum;
            float* og = out + (size_t)(b*G_ + g0 + g)*NODE_;
            for (int n = part; n < NODE_; n += 8)
                og[n] = sc_lds[g*SCST_ + n] * rs;
        }
    }
}

extern "C" void kernel_launch(void* const* d_in, const int* in_sizes, int n_in,
                              void* d_out, int out_size, void* d_ws, size_t ws_size,
                              hipStream_t stream) {
    (void)in_sizes; (void)n_in; (void)out_size; (void)ws_size;
    const float* graph     = (const float*)d_in[0];
    const float* capacity  = (const float*)d_in[1];
    const float* sols_mask = (const float*)d_in[2];
    const float* ninf_mask = (const float*)d_in[3];
    const float* enc       = (const float*)d_in[4];
    const float* Wq        = (const float*)d_in[5];
    const float* Wk        = (const float*)d_in[6];
    const float* Wv        = (const float*)d_in[7];
    const float* Wc        = (const float*)d_in[8];
    const float* bc        = (const float*)d_in[9];
    const float* Wkl       = (const float*)d_in[10];
    float* out = (float*)d_out;

    float* ws   = (float*)d_ws;
    float* kT   = ws;                       // B*E*M      = 9,830,400 f
    float* vbuf = ws + 9830400;             // B*M*E      = 9,830,400 f
    float* shkT = ws + 19660800;            // B*E*NODE   = 6,553,600 f
    float* qb   = ws + 26214400;            // B*E        = 32,768 f   (~105 MB total)

    qbase_kernel<<<B_, 128, 0, stream>>>(graph, Wq, qb);
    proj_kernel<<<dim3(10, B_), 256, 0, stream>>>(enc, Wk, Wv, Wkl, kT, vbuf, shkT);
    attn_kernel<<<dim3(8, B_), 256, 0, stream>>>(capacity, sols_mask, ninf_mask,
                                                 Wq, Wc, bc, kT, vbuf, shkT, qb, out);
}

// Round 2
// 455.666 us; speedup vs baseline: 3.9978x; 3.9978x over previous
//
#include <hip/hip_runtime.h>

#define B_    256
#define G_    200
#define S_    100
#define NODE_ 200
#define E_    128
#define H_    8
#define M_    300
#define MT_   19     // m tiles of 16 (304 padded)
#define NT_   13     // n/g tiles of 16 (208 padded)
#define CLIP_ 10.0f

typedef float f32x4 __attribute__((ext_vector_type(4)));
typedef short s16x4 __attribute__((ext_vector_type(4)));
typedef short s16x8 __attribute__((ext_vector_type(8)));

#define MFMA16(A, B, C) __builtin_amdgcn_mfma_f32_16x16x32_bf16(A, B, C, 0, 0, 0)

// ---- split-bf16 helpers: x ~= hi + lo with ~2^-17 relative error ----
__device__ __forceinline__ unsigned bf16u(float x) {
    unsigned u = __builtin_bit_cast(unsigned, x);
    return (u + 0x7fffu + ((u >> 16) & 1u)) >> 16;
}
__device__ __forceinline__ float bfbits(unsigned hb16) {           // bf16 bits -> float
    return __builtin_bit_cast(float, hb16 << 16);
}
__device__ __forceinline__ short bfhi(float x) { return (short)bf16u(x); }
__device__ __forceinline__ short bflo(float x, short hi) {
    float hf = __builtin_bit_cast(float, ((unsigned)(unsigned short)hi) << 16);
    return (short)bf16u(x - hf);
}
__device__ __forceinline__ s16x8 cat8(s16x4 a, s16x4 b) {
    s16x8 r; r[0]=a[0]; r[1]=a[1]; r[2]=a[2]; r[3]=a[3];
             r[4]=b[0]; r[5]=b[1]; r[6]=b[2]; r[7]=b[3]; return r;
}

// =================== setup: W fragments (B-frag layout, split) ===================
// wf[p][ct][kc][l][j] = W_p[kc*16 + (l>>4)*4 + j][ct*16 + (l&15)],  p: 0=Wk 1=Wv 2=Wkl 3=Wc
__global__ __launch_bounds__(64) void wfrag_kernel(
    const float* __restrict__ Wk, const float* __restrict__ Wv,
    const float* __restrict__ Wl, const float* __restrict__ Wc,
    short* __restrict__ wf_hi, short* __restrict__ wf_lo)
{
    const int p = blockIdx.x, ct = blockIdx.y;
    const int l = threadIdx.x, qq = l >> 4, li = l & 15;
    const float* W = (p == 0) ? Wk : ((p == 1) ? Wv : ((p == 2) ? Wl : Wc));
    for (int kc = 0; kc < 8; ++kc) {
        s16x4 hi, lo;
        #pragma unroll
        for (int j = 0; j < 4; ++j) {
            float v = W[(kc*16 + qq*4 + j)*E_ + ct*16 + li];
            short h = bfhi(v); hi[j] = h; lo[j] = bflo(v, h);
        }
        const int ix = (((p*8 + ct)*8 + kc)*64 + l)*4;
        *(s16x4*)(wf_hi + ix) = hi;
        *(s16x4*)(wf_lo + ix) = lo;
    }
}

// =================== qbase[b][c] = graph[b] @ Wq[:128] ===================
__global__ __launch_bounds__(128) void qbase_kernel(
    const float* __restrict__ graph, const float* __restrict__ Wq,
    float* __restrict__ qbase)
{
    const int b = blockIdx.x, c = threadIdx.x;
    __shared__ float gs[E_];
    gs[c] = graph[b*E_ + c];
    __syncthreads();
    float acc = 0.f;
    #pragma unroll 8
    for (int e = 0; e < E_; ++e) acc += gs[e] * Wq[e*E_ + c];
    qbase[b*E_ + c] = acc;
}

// =================== proj: k/v/shk fragments (MFMA, split) ===================
// kf[h][mt][l][j]  = k[mt*16 + (l&15)][h*16 + (l>>4)*4 + j]      (A-frag for scores; LDS-transposed)
// vf[h][mt][l][j]  = v[mt*16 + (l>>4)*4 + j][h*16 + (l&15)]      (A-frag for PV; direct D-layout)
// sf[nt][jt][l][j] = shk[nt*16 + (l&15)][jt*16 + (l>>4)*4 + j]   (A-frag for final; LDS-transposed)
__global__ __launch_bounds__(64) void proj_kernel(
    const float* __restrict__ enc,
    const short* __restrict__ wf_hi, const short* __restrict__ wf_lo,
    short* __restrict__ kf_hi, short* __restrict__ kf_lo,
    short* __restrict__ vf_hi, short* __restrict__ vf_lo,
    short* __restrict__ sf_hi, short* __restrict__ sf_lo)
{
    int id = blockIdx.x;                       // 4864 = 8*608: XCD-chunked swizzle
    { const int xcd = id & 7, pos = id >> 3; id = xcd*608 + pos; }
    const int b = id / MT_, mt = id % MT_;
    const int l = threadIdx.x, qq = l >> 4, li = l & 15;
    const int m = mt*16 + li;

    // A fragments from enc (4 K-chunks of 32), zero-padded rows m>=300
    s16x8 Ahi[4], Alo[4];
    #pragma unroll
    for (int u = 0; u < 4; ++u) {
        float va[8];
        if (m < M_) {
            const float* ep = enc + ((size_t)b*M_ + m)*E_ + u*32 + qq*4;
            float4 f0 = *(const float4*)ep;
            float4 f1 = *(const float4*)(ep + 16);
            va[0]=f0.x; va[1]=f0.y; va[2]=f0.z; va[3]=f0.w;
            va[4]=f1.x; va[5]=f1.y; va[6]=f1.z; va[7]=f1.w;
        } else {
            #pragma unroll
            for (int j = 0; j < 8; ++j) va[j] = 0.f;
        }
        #pragma unroll
        for (int j = 0; j < 8; ++j) {
            short h = bfhi(va[j]); Ahi[u][j] = h; Alo[u][j] = bflo(va[j], h);
        }
    }

    __shared__ unsigned tile[16*17];

    #pragma unroll
    for (int p = 0; p < 3; ++p) {
        if (p == 2 && mt >= NT_) break;        // shk only has 13 row tiles
        #pragma unroll
        for (int ct = 0; ct < 8; ++ct) {
            f32x4 acc = {0.f, 0.f, 0.f, 0.f};
            #pragma unroll
            for (int u = 0; u < 4; ++u) {
                const int base = (((p*8 + ct)*8 + 2*u)*64 + l)*4;
                s16x8 Bh = cat8(*(const s16x4*)(wf_hi + base), *(const s16x4*)(wf_hi + base + 256));
                s16x8 Bl = cat8(*(const s16x4*)(wf_lo + base), *(const s16x4*)(wf_lo + base + 256));
                acc = MFMA16(Ahi[u], Bh, acc);
                acc = MFMA16(Ahi[u], Bl, acc);
                acc = MFMA16(Alo[u], Bh, acc);
            }
            if (p == 1) {                       // v: D-layout is already the PV A-frag
                s16x4 oh, ol;
                #pragma unroll
                for (int r = 0; r < 4; ++r) { short h = bfhi(acc[r]); oh[r] = h; ol[r] = bflo(acc[r], h); }
                const size_t ix = (((size_t)(b*8 + ct))*MT_ + mt)*256 + (size_t)l*4;
                *(s16x4*)(vf_hi + ix) = oh;
                *(s16x4*)(vf_lo + ix) = ol;
            } else {                            // k / shk: transpose via LDS bounce
                #pragma unroll
                for (int r = 0; r < 4; ++r) {
                    short h = bfhi(acc[r]); short lo = bflo(acc[r], h);
                    tile[(qq*4 + r)*17 + li] = (((unsigned)(unsigned short)h) << 16) | (unsigned short)(unsigned)lo;
                }
                __syncthreads();
                s16x4 oh, ol;
                #pragma unroll
                for (int j = 0; j < 4; ++j) {
                    unsigned w = tile[li*17 + qq*4 + j];
                    oh[j] = (short)(w >> 16); ol[j] = (short)(w & 0xffffu);
                }
                if (p == 0) {
                    const size_t ix = (((size_t)(b*8 + ct))*MT_ + mt)*256 + (size_t)l*4;
                    *(s16x4*)(kf_hi + ix) = oh;
                    *(s16x4*)(kf_lo + ix) = ol;
                } else {
                    const size_t ix = (((size_t)(b*NT_ + mt))*8 + ct)*256 + (size_t)l*4;
                    *(s16x4*)(sf_hi + ix) = oh;
                    *(s16x4*)(sf_lo + ix) = ol;
                }
                __syncthreads();
            }
        }
    }
}

// =================== attn1: scores+softmax+PV+Wc -> mhfrag (fp32) ===================
// 1 wave per (b, g-tile). scoresT[m][g] kept in regs; P regs ARE the PV B-fragments.
__global__ __launch_bounds__(64) void attn1_kernel(
    const float* __restrict__ capacity, const float* __restrict__ sols_mask,
    const float* __restrict__ ninf_mask, const float* __restrict__ Wq,
    const float* __restrict__ bc_, const float* __restrict__ qbase,
    const short* __restrict__ kf_hi, const short* __restrict__ kf_lo,
    const short* __restrict__ vf_hi, const short* __restrict__ vf_lo,
    const short* __restrict__ wf_hi, const short* __restrict__ wf_lo,
    float* __restrict__ mhfrag)
{
    int id = blockIdx.x;                       // 3328 = 8*416
    { const int xcd = id & 7, pos = id >> 3; id = xcd*416 + pos; }
    const int b = id / NT_, gt = id % NT_;
    const int l = threadIdx.x, qq = l >> 4, li = l & 15;
    const int g0 = gt*16;

    __shared__ short qhi_l[8*64*4], qlo_l[8*64*4];
    __shared__ float out_l[8*64*4];

    // ---- q staging: q[g][c] = qbase[b][c] + cap*Wq[128][c], split ----
    {
        const int gg = (g0 + li < G_) ? (g0 + li) : (G_ - 1);
        const float cap = capacity[b*G_ + gg];
        #pragma unroll
        for (int h = 0; h < 8; ++h) {
            const int c = h*16 + qq*4;
            float4 qb = *(const float4*)(qbase + b*E_ + c);
            float4 wl = *(const float4*)(Wq + E_*E_ + c);
            float vv[4] = {qb.x + cap*wl.x, qb.y + cap*wl.y, qb.z + cap*wl.z, qb.w + cap*wl.w};
            s16x4 hi, lo;
            #pragma unroll
            for (int j = 0; j < 4; ++j) { short h2 = bfhi(vv[j]); hi[j] = h2; lo[j] = bflo(vv[j], h2); }
            *(s16x4*)(qhi_l + (h*64 + l)*4) = hi;
            *(s16x4*)(qlo_l + (h*64 + l)*4) = lo;
        }
    }
    // ---- masks -> packed bf16 regs (exact for the zero masks in this op) ----
    unsigned mpk[MT_][2];
    {
        const int gg = (g0 + li < G_) ? (g0 + li) : (G_ - 1);
        const float* nb = ninf_mask + ((size_t)b*G_ + gg)*NODE_;
        const float* sb = sols_mask + ((size_t)b*G_ + gg)*S_;
        #pragma unroll
        for (int mt = 0; mt < MT_; ++mt) {
            unsigned p0 = 0, p1 = 0;
            #pragma unroll
            for (int r = 0; r < 4; ++r) {
                const int m = mt*16 + qq*4 + r;
                float mv = (m < NODE_) ? nb[m] : ((m < M_) ? sb[m - NODE_] : -3.0e38f);
                unsigned hb = bf16u(mv);
                if (r == 0) p0 = hb;        else if (r == 1) p0 |= hb << 16;
                else if (r == 2) p1 = hb;   else p1 |= hb << 16;
            }
            mpk[mt][0] = p0; mpk[mt][1] = p1;
        }
    }
    __syncthreads();

    const bool isN12 = (qq < 2);           // tile 12 rows m=192..199 are nodes iff qq<2
    const s16x4 z4 = {0, 0, 0, 0};

    #pragma unroll 1
    for (int h = 0; h < H_; ++h) {
        // q B-fragment (K padded 16->32: slots 4..7 zero in BOTH operands)
        s16x8 qBh = cat8(*(const s16x4*)(qhi_l + (h*64 + l)*4), z4);
        s16x8 qBl = cat8(*(const s16x4*)(qlo_l + (h*64 + l)*4), z4);

        // ---- scoresT[m][g]: 19 independent MFMA tiles ----
        f32x4 sc[MT_];
        const size_t kb = (((size_t)(b*8 + h))*MT_)*256 + (size_t)l*4;
        #pragma unroll
        for (int mt = 0; mt < MT_; ++mt) {
            s16x8 Ah = cat8(*(const s16x4*)(kf_hi + kb + (size_t)mt*256), z4);
            s16x8 Al = cat8(*(const s16x4*)(kf_lo + kb + (size_t)mt*256), z4);
            f32x4 a = {0.f, 0.f, 0.f, 0.f};
            a = MFMA16(Ah, qBh, a);
            a = MFMA16(Ah, qBl, a);
            a = MFMA16(Al, qBh, a);
            sc[mt] = a;
        }
        // ---- scale + mask ----
        #pragma unroll
        for (int mt = 0; mt < MT_; ++mt) {
            sc[mt][0] = sc[mt][0]*0.25f + bfbits(mpk[mt][0] & 0xffffu);
            sc[mt][1] = sc[mt][1]*0.25f + bfbits(mpk[mt][0] >> 16);
            sc[mt][2] = sc[mt][2]*0.25f + bfbits(mpk[mt][1] & 0xffffu);
            sc[mt][3] = sc[mt][3]*0.25f + bfbits(mpk[mt][1] >> 16);
        }
        // ---- segmented softmax (nodes m<200 | sols m>=200), per-g over lanes {l,l^16,l^32,l^48} ----
        float mxN = -3.0e38f, mxS = -3.0e38f;
        #pragma unroll
        for (int mt = 0; mt < 12; ++mt)
            #pragma unroll
            for (int r = 0; r < 4; ++r) mxN = fmaxf(mxN, sc[mt][r]);
        #pragma unroll
        for (int r = 0; r < 4; ++r) {
            float v = sc[12][r];
            mxN = isN12 ? fmaxf(mxN, v) : mxN;
            mxS = isN12 ? mxS : fmaxf(mxS, v);
        }
        #pragma unroll
        for (int mt = 13; mt < MT_; ++mt)
            #pragma unroll
            for (int r = 0; r < 4; ++r) mxS = fmaxf(mxS, sc[mt][r]);
        mxN = fmaxf(mxN, __shfl_xor(mxN, 16)); mxN = fmaxf(mxN, __shfl_xor(mxN, 32));
        mxS = fmaxf(mxS, __shfl_xor(mxS, 16)); mxS = fmaxf(mxS, __shfl_xor(mxS, 32));

        float sN = 0.f, sS = 0.f;
        #pragma unroll
        for (int mt = 0; mt < 12; ++mt)
            #pragma unroll
            for (int r = 0; r < 4; ++r) { float e = __expf(sc[mt][r] - mxN); sc[mt][r] = e; sN += e; }
        {
            const float mx12 = isN12 ? mxN : mxS;
            #pragma unroll
            for (int r = 0; r < 4; ++r) {
                float e = __expf(sc[12][r] - mx12); sc[12][r] = e;
                sN += isN12 ? e : 0.f; sS += isN12 ? 0.f : e;
            }
        }
        #pragma unroll
        for (int mt = 13; mt < MT_; ++mt)
            #pragma unroll
            for (int r = 0; r < 4; ++r) { float e = __expf(sc[mt][r] - mxS); sc[mt][r] = e; sS += e; }
        sN += __shfl_xor(sN, 16); sN += __shfl_xor(sN, 32);
        sS += __shfl_xor(sS, 16); sS += __shfl_xor(sS, 32);
        const float rN = 1.f / sN, rS = 1.f / sS;
        #pragma unroll
        for (int mt = 0; mt < 12; ++mt)
            #pragma unroll
            for (int r = 0; r < 4; ++r) sc[mt][r] *= rN;
        { const float r12 = isN12 ? rN : rS;
          #pragma unroll
          for (int r = 0; r < 4; ++r) sc[12][r] *= r12; }
        #pragma unroll
        for (int mt = 13; mt < MT_; ++mt)
            #pragma unroll
            for (int r = 0; r < 4; ++r) sc[mt][r] *= rS;

        // ---- PV: outT[k2][g] += V^T * P ; P regs are already B-fragments ----
        f32x4 oA = {0.f,0.f,0.f,0.f}, oB = {0.f,0.f,0.f,0.f};
        const size_t vb = (((size_t)(b*8 + h))*MT_)*256 + (size_t)l*4;
        #pragma unroll
        for (int t = 0; t < 10; ++t) {
            const int mA = 2*t, mB = 2*t + 1;
            s16x4 ph0, pl0, ph1, pl1;
            #pragma unroll
            for (int j = 0; j < 4; ++j) { short hh = bfhi(sc[mA][j]); ph0[j] = hh; pl0[j] = bflo(sc[mA][j], hh); }
            s16x4 vA_h = *(const s16x4*)(vf_hi + vb + (size_t)mA*256);
            s16x4 vA_l = *(const s16x4*)(vf_lo + vb + (size_t)mA*256);
            s16x4 vB_h = z4, vB_l = z4;
            if (t < 9) {
                #pragma unroll
                for (int j = 0; j < 4; ++j) { short hh = bfhi(sc[mB][j]); ph1[j] = hh; pl1[j] = bflo(sc[mB][j], hh); }
                vB_h = *(const s16x4*)(vf_hi + vb + (size_t)mB*256);
                vB_l = *(const s16x4*)(vf_lo + vb + (size_t)mB*256);
            } else { ph1 = z4; pl1 = z4; }
            s16x8 Ah = cat8(vA_h, vB_h), Al = cat8(vA_l, vB_l);
            s16x8 Bh = cat8(ph0, ph1),   Bl = cat8(pl0, pl1);
            if (t & 1) { oB = MFMA16(Ah, Bh, oB); oB = MFMA16(Ah, Bl, oB); oB = MFMA16(Al, Bh, oB); }
            else       { oA = MFMA16(Ah, Bh, oA); oA = MFMA16(Ah, Bl, oA); oA = MFMA16(Al, Bh, oA); }
        }
        f32x4 osum = oA + oB;
        *(f32x4*)(out_l + (h*64 + l)*4) = osum;
    }
    __syncthreads();

    // ---- mhT[j][g] = Wc^T * outT + bc ; out regs re-packed as B-fragments ----
    s16x8 Bh[4], Bl[4];
    #pragma unroll
    for (int u = 0; u < 4; ++u) {
        f32x4 a0 = *(const f32x4*)(out_l + ((2*u)*64 + l)*4);
        f32x4 a1 = *(const f32x4*)(out_l + ((2*u + 1)*64 + l)*4);
        #pragma unroll
        for (int j = 0; j < 4; ++j) {
            short h0 = bfhi(a0[j]); Bh[u][j]   = h0; Bl[u][j]   = bflo(a0[j], h0);
            short h1 = bfhi(a1[j]); Bh[u][4+j] = h1; Bl[u][4+j] = bflo(a1[j], h1);
        }
    }
    #pragma unroll
    for (int jt = 0; jt < 8; ++jt) {
        f32x4 acc = {0.f, 0.f, 0.f, 0.f};
        #pragma unroll
        for (int u = 0; u < 4; ++u) {
            const int base = (((3*8 + jt)*8 + 2*u)*64 + l)*4;
            s16x8 Ah = cat8(*(const s16x4*)(wf_hi + base), *(const s16x4*)(wf_hi + base + 256));
            s16x8 Al = cat8(*(const s16x4*)(wf_lo + base), *(const s16x4*)(wf_lo + base + 256));
            acc = MFMA16(Ah, Bh[u], acc);
            acc = MFMA16(Ah, Bl[u], acc);
            acc = MFMA16(Al, Bh[u], acc);
        }
        float4 b4 = *(const float4*)(bc_ + jt*16 + qq*4);
        acc[0] += b4.x; acc[1] += b4.y; acc[2] += b4.z; acc[3] += b4.w;
        *(f32x4*)(mhfrag + (((size_t)(b*NT_ + gt))*8 + jt)*256 + (size_t)l*4) = acc;
    }
}

// =================== attn2: final logits GEMM + tanh + mask + softmax ===================
__global__ __launch_bounds__(64) void attn2_kernel(
    const float* __restrict__ ninf_mask,
    const short* __restrict__ sf_hi, const short* __restrict__ sf_lo,
    const float* __restrict__ mhfrag,
    float* __restrict__ out)
{
    int id = blockIdx.x;
    { const int xcd = id & 7, pos = id >> 3; id = xcd*416 + pos; }
    const int b = id / NT_, gt = id % NT_;
    const int l = threadIdx.x, qq = l >> 4, li = l & 15;
    const int g0 = gt*16;

    // mh B-fragments (split on load; mh stored fp32 -> no precision loss)
    s16x8 Bh[4], Bl[4];
    #pragma unroll
    for (int u = 0; u < 4; ++u) {
        f32x4 m0 = *(const f32x4*)(mhfrag + (((size_t)(b*NT_ + gt))*8 + 2*u)*256 + (size_t)l*4);
        f32x4 m1 = *(const f32x4*)(mhfrag + (((size_t)(b*NT_ + gt))*8 + 2*u + 1)*256 + (size_t)l*4);
        #pragma unroll
        for (int j = 0; j < 4; ++j) {
            short h0 = bfhi(m0[j]); Bh[u][j]   = h0; Bl[u][j]   = bflo(m0[j], h0);
            short h1 = bfhi(m1[j]); Bh[u][4+j] = h1; Bl[u][4+j] = bflo(m1[j], h1);
        }
    }
    // zT[n][g] over 13 n-tiles
    f32x4 z[NT_];
    #pragma unroll
    for (int nt = 0; nt < NT_; ++nt) {
        f32x4 acc = {0.f, 0.f, 0.f, 0.f};
        #pragma unroll
        for (int u = 0; u < 4; ++u) {
            const size_t base = (((size_t)(b*NT_ + nt))*8 + 2*u)*256 + (size_t)l*4;
            s16x8 Ah = cat8(*(const s16x4*)(sf_hi + base), *(const s16x4*)(sf_hi + base + 256));
            s16x8 Al = cat8(*(const s16x4*)(sf_lo + base), *(const s16x4*)(sf_lo + base + 256));
            acc = MFMA16(Ah, Bh[u], acc);
            acc = MFMA16(Ah, Bl[u], acc);
            acc = MFMA16(Al, Bh[u], acc);
        }
        z[nt] = acc;
    }
    // logits = 10*tanh(z/sqrt(E)) + ninf
    const float rE = 0.08838834764831845f;
    const int ggl = (g0 + li < G_) ? (g0 + li) : (G_ - 1);
    const float* nb = ninf_mask + ((size_t)b*G_ + ggl)*NODE_;
    #pragma unroll
    for (int nt = 0; nt < NT_; ++nt) {
        #pragma unroll
        for (int r = 0; r < 4; ++r) {
            const int n = nt*16 + qq*4 + r;
            float lg;
            if (nt < 12 || (qq*4 + r) < 8) {
                float a2 = z[nt][r] * rE;
                float ex = __expf(2.f * a2);
                float th = 1.f - 2.f / (ex + 1.f);
                lg = CLIP_*th + nb[n];
            } else lg = -3.0e38f;
            z[nt][r] = lg;
        }
    }
    // row softmax over n (per g = l&15, across lanes {l, l^16, l^32, l^48})
    float mx = -3.0e38f;
    #pragma unroll
    for (int nt = 0; nt < NT_; ++nt)
        #pragma unroll
        for (int r = 0; r < 4; ++r) mx = fmaxf(mx, z[nt][r]);
    mx = fmaxf(mx, __shfl_xor(mx, 16)); mx = fmaxf(mx, __shfl_xor(mx, 32));
    float sm = 0.f;
    #pragma unroll
    for (int nt = 0; nt < NT_; ++nt)
        #pragma unroll
        for (int r = 0; r < 4; ++r) { float e = __expf(z[nt][r] - mx); z[nt][r] = e; sm += e; }
    sm += __shfl_xor(sm, 16); sm += __shfl_xor(sm, 32);
    const float rs = 1.f / sm;

    // transpose via LDS in 64-n chunks, coalesced stores
    __shared__ float tl[16*69];
    float* ob = out + (size_t)b*G_*NODE_;
    #pragma unroll
    for (int ch = 0; ch < 4; ++ch) {
        const int ntn = (ch < 3) ? 4 : 1;
        for (int k = 0; k < ntn; ++k) {
            const int nt = ch*4 + k;
            #pragma unroll
            for (int r = 0; r < 4; ++r)
                tl[li*69 + k*16 + qq*4 + r] = z[nt][r] * rs;
        }
        __syncthreads();
        const int n = ch*64 + l;
        const bool nok = (ch < 3) || (l < 8);
        #pragma unroll
        for (int gi = 0; gi < 16; ++gi) {
            const int g = g0 + gi;
            if (nok && g < G_) ob[(size_t)g*NODE_ + n] = tl[gi*69 + l];
        }
        __syncthreads();
    }
}

// =================== launch ===================
extern "C" void kernel_launch(void* const* d_in, const int* in_sizes, int n_in,
                              void* d_out, int out_size, void* d_ws, size_t ws_size,
                              hipStream_t stream) {
    (void)in_sizes; (void)n_in; (void)out_size; (void)ws_size;
    const float* graph = (const float*)d_in[0];
    const float* capacity = (const float*)d_in[1];
    const float* sols_mask = (const float*)d_in[2];
    const float* ninf_mask = (const float*)d_in[3];
    const float* enc = (const float*)d_in[4];
    const float* Wq  = (const float*)d_in[5];
    const float* Wk  = (const float*)d_in[6];
    const float* Wv  = (const float*)d_in[7];
    const float* Wc  = (const float*)d_in[8];
    const float* bc  = (const float*)d_in[9];
    const float* Wkl = (const float*)d_in[10];
    float* out = (float*)d_out;

    // ws layout (bytes), total 94,765,056 < proven >=105 MB
    char* wsb = (char*)d_ws;
    short* kf_hi = (short*)(wsb);
    short* kf_lo = (short*)(wsb + 19922944);
    short* sf_hi = (short*)(wsb + 39845888);
    short* sf_lo = (short*)(wsb + 53477376);
    float* mh    = (float*)(wsb + 67108864);
    short* wf_hi = (short*)(wsb + 94371840);
    short* wf_lo = (short*)(wsb + 94502912);
    float* qb    = (float*)(wsb + 94633984);
    // v fragments live in d_out (dead before attn2 overwrites it): 39.85MB <= 40.96MB
    short* vf_hi = (short*)d_out;
    short* vf_lo = (short*)d_out + 9961472;

    wfrag_kernel<<<dim3(4, 8), 64, 0, stream>>>(Wk, Wv, Wkl, Wc, wf_hi, wf_lo);
    qbase_kernel<<<B_, 128, 0, stream>>>(graph, Wq, qb);
    proj_kernel<<<MT_*B_, 64, 0, stream>>>(enc, wf_hi, wf_lo, kf_hi, kf_lo, vf_hi, vf_lo, sf_hi, sf_lo);
    attn1_kernel<<<NT_*B_, 64, 0, stream>>>(capacity, sols_mask, ninf_mask, Wq, bc, qb,
                                            kf_hi, kf_lo, vf_hi, vf_lo, wf_hi, wf_lo, mh);
    attn2_kernel<<<NT_*B_, 64, 0, stream>>>(ninf_mask, sf_hi, sf_lo, mh, out);
}

// Round 3
// 441.639 us; speedup vs baseline: 4.1247x; 1.0318x over previous
//
#include <hip/hip_runtime.h>

#define B_    256
#define G_    200
#define S_    100
#define NODE_ 200
#define E_    128
#define H_    8
#define M_    300
#define MT_   19     // m tiles of 16 (304 padded)
#define NT_   13     // n/g tiles of 16 (208 padded)
#define CLIP_ 10.0f

typedef float f32x4 __attribute__((ext_vector_type(4)));
typedef short s16x4 __attribute__((ext_vector_type(4)));
typedef short s16x8 __attribute__((ext_vector_type(8)));

#define MFMA16(A, B, C) __builtin_amdgcn_mfma_f32_16x16x32_bf16(A, B, C, 0, 0, 0)

// ---- split-bf16 helpers: x ~= hi + lo with ~2^-17 relative error ----
__device__ __forceinline__ unsigned bf16u(float x) {
    unsigned u = __builtin_bit_cast(unsigned, x);
    return (u + 0x7fffu + ((u >> 16) & 1u)) >> 16;
}
__device__ __forceinline__ float bfbits(unsigned hb16) {
    return __builtin_bit_cast(float, hb16 << 16);
}
__device__ __forceinline__ short bfhi(float x) { return (short)bf16u(x); }
__device__ __forceinline__ short bflo(float x, short hi) {
    float hf = __builtin_bit_cast(float, ((unsigned)(unsigned short)hi) << 16);
    return (short)bf16u(x - hf);
}
__device__ __forceinline__ s16x8 cat8(s16x4 a, s16x4 b) {
    s16x8 r; r[0]=a[0]; r[1]=a[1]; r[2]=a[2]; r[3]=a[3];
             r[4]=b[0]; r[5]=b[1]; r[6]=b[2]; r[7]=b[3]; return r;
}
__device__ __forceinline__ f32x4 max4(f32x4 a, f32x4 b) {
    f32x4 r; r[0]=fmaxf(a[0],b[0]); r[1]=fmaxf(a[1],b[1]);
             r[2]=fmaxf(a[2],b[2]); r[3]=fmaxf(a[3],b[3]); return r;
}

// =================== setup: W fragments (B-frag layout, split) ===================
// wf[p][ct][kc][l][j] = W_p[kc*16 + (l>>4)*4 + j][ct*16 + (l&15)],  p: 0=Wk 1=Wv 2=Wkl 3=Wc
__global__ __launch_bounds__(64) void wfrag_kernel(
    const float* __restrict__ Wk, const float* __restrict__ Wv,
    const float* __restrict__ Wl, const float* __restrict__ Wc,
    short* __restrict__ wf_hi, short* __restrict__ wf_lo)
{
    const int p = blockIdx.x, ct = blockIdx.y;
    const int l = threadIdx.x, qq = l >> 4, li = l & 15;
    const float* W = (p == 0) ? Wk : ((p == 1) ? Wv : ((p == 2) ? Wl : Wc));
    for (int kc = 0; kc < 8; ++kc) {
        s16x4 hi, lo;
        #pragma unroll
        for (int j = 0; j < 4; ++j) {
            float v = W[(kc*16 + qq*4 + j)*E_ + ct*16 + li];
            short h = bfhi(v); hi[j] = h; lo[j] = bflo(v, h);
        }
        const int ix = (((p*8 + ct)*8 + kc)*64 + l)*4;
        *(s16x4*)(wf_hi + ix) = hi;
        *(s16x4*)(wf_lo + ix) = lo;
    }
}

// =================== qbase[b][c] = graph[b] @ Wq[:128] ===================
__global__ __launch_bounds__(128) void qbase_kernel(
    const float* __restrict__ graph, const float* __restrict__ Wq,
    float* __restrict__ qbase)
{
    const int b = blockIdx.x, c = threadIdx.x;
    __shared__ float gs[E_];
    gs[c] = graph[b*E_ + c];
    __syncthreads();
    float acc = 0.f;
    #pragma unroll 8
    for (int e = 0; e < E_; ++e) acc += gs[e] * Wq[e*E_ + c];
    qbase[b*E_ + c] = acc;
}

// =================== proj: k/v/shk fragments (MFMA, split) ===================
__global__ __launch_bounds__(64, 4) void proj_kernel(
    const float* __restrict__ enc,
    const short* __restrict__ wf_hi, const short* __restrict__ wf_lo,
    short* __restrict__ kf_hi, short* __restrict__ kf_lo,
    short* __restrict__ vf_hi, short* __restrict__ vf_lo,
    short* __restrict__ sf_hi, short* __restrict__ sf_lo)
{
    int id = blockIdx.x;                       // 4864 = 8*608: XCD-chunked swizzle
    { const int xcd = id & 7, pos = id >> 3; id = xcd*608 + pos; }
    const int b = id / MT_, mt = id % MT_;
    const int l = threadIdx.x, qq = l >> 4, li = l & 15;
    const int m = mt*16 + li;

    s16x8 Ahi[4], Alo[4];
    #pragma unroll
    for (int u = 0; u < 4; ++u) {
        float va[8];
        if (m < M_) {
            const float* ep = enc + ((size_t)b*M_ + m)*E_ + u*32 + qq*4;
            float4 f0 = *(const float4*)ep;
            float4 f1 = *(const float4*)(ep + 16);
            va[0]=f0.x; va[1]=f0.y; va[2]=f0.z; va[3]=f0.w;
            va[4]=f1.x; va[5]=f1.y; va[6]=f1.z; va[7]=f1.w;
        } else {
            #pragma unroll
            for (int j = 0; j < 8; ++j) va[j] = 0.f;
        }
        #pragma unroll
        for (int j = 0; j < 8; ++j) {
            short h = bfhi(va[j]); Ahi[u][j] = h; Alo[u][j] = bflo(va[j], h);
        }
    }

    __shared__ unsigned tile[16*17];

    #pragma unroll
    for (int p = 0; p < 3; ++p) {
        if (p == 2 && mt >= NT_) break;
        #pragma unroll
        for (int ct = 0; ct < 8; ++ct) {
            f32x4 acc = {0.f, 0.f, 0.f, 0.f};
            #pragma unroll
            for (int u = 0; u < 4; ++u) {
                const int base = (((p*8 + ct)*8 + 2*u)*64 + l)*4;
                s16x8 Bh = cat8(*(const s16x4*)(wf_hi + base), *(const s16x4*)(wf_hi + base + 256));
                s16x8 Bl = cat8(*(const s16x4*)(wf_lo + base), *(const s16x4*)(wf_lo + base + 256));
                acc = MFMA16(Ahi[u], Bh, acc);
                acc = MFMA16(Ahi[u], Bl, acc);
                acc = MFMA16(Alo[u], Bh, acc);
            }
            if (p == 1) {
                s16x4 oh, ol;
                #pragma unroll
                for (int r = 0; r < 4; ++r) { short h = bfhi(acc[r]); oh[r] = h; ol[r] = bflo(acc[r], h); }
                const size_t ix = (((size_t)(b*8 + ct))*MT_ + mt)*256 + (size_t)l*4;
                *(s16x4*)(vf_hi + ix) = oh;
                *(s16x4*)(vf_lo + ix) = ol;
            } else {
                #pragma unroll
                for (int r = 0; r < 4; ++r) {
                    short h = bfhi(acc[r]); short lo = bflo(acc[r], h);
                    tile[(qq*4 + r)*17 + li] = (((unsigned)(unsigned short)h) << 16) | (unsigned short)(unsigned)lo;
                }
                __syncthreads();
                s16x4 oh, ol;
                #pragma unroll
                for (int j = 0; j < 4; ++j) {
                    unsigned w = tile[li*17 + qq*4 + j];
                    oh[j] = (short)(w >> 16); ol[j] = (short)(w & 0xffffu);
                }
                if (p == 0) {
                    const size_t ix = (((size_t)(b*8 + ct))*MT_ + mt)*256 + (size_t)l*4;
                    *(s16x4*)(kf_hi + ix) = oh;
                    *(s16x4*)(kf_lo + ix) = ol;
                } else {
                    const size_t ix = (((size_t)(b*NT_ + mt))*8 + ct)*256 + (size_t)l*4;
                    *(s16x4*)(sf_hi + ix) = oh;
                    *(s16x4*)(sf_lo + ix) = ol;
                }
                __syncthreads();
            }
        }
    }
}

// =================== attn1: scores+softmax+PV for 2 heads -> outws ===================
// grid = B*NT*4 single-wave blocks; head-group hg covers heads {2hg, 2hg+1}.
__global__ __launch_bounds__(64, 4) void attn1_kernel(
    const float* __restrict__ capacity, const float* __restrict__ sols_mask,
    const float* __restrict__ ninf_mask, const float* __restrict__ Wq,
    const float* __restrict__ qbase,
    const short* __restrict__ kf_hi, const short* __restrict__ kf_lo,
    const short* __restrict__ vf_hi, const short* __restrict__ vf_lo,
    float* __restrict__ outws)
{
    int id = blockIdx.x;                       // 13312 = 8*1664
    { const int xcd = id & 7, pos = id >> 3; id = xcd*1664 + pos; }
    const int b  = id / (NT_*4);
    const int r0 = id % (NT_*4);
    const int gt = r0 >> 2, hg = r0 & 3;
    const int l = threadIdx.x, qq = l >> 4, li = l & 15;
    const int g0 = gt*16;

    __shared__ unsigned mlds[MT_][64][2];      // 9728 B: bf16-packed masks

    const int gg = (g0 + li < G_) ? (g0 + li) : (G_ - 1);
    // ---- stage masks to LDS (bf16-packed per lane) ----
    {
        const float* nb = ninf_mask + ((size_t)b*G_ + gg)*NODE_;
        const float* sb = sols_mask + ((size_t)b*G_ + gg)*S_;
        #pragma unroll
        for (int mt = 0; mt < MT_; ++mt) {
            const int m = mt*16 + qq*4;        // multiples of 4; never straddles 200/300
            float4 mv;
            if (m < NODE_)      mv = *(const float4*)(nb + m);
            else if (m < M_)    mv = *(const float4*)(sb + m - NODE_);
            else                mv = make_float4(-3.0e38f, -3.0e38f, -3.0e38f, -3.0e38f);
            unsigned p0 = bf16u(mv.x) | (bf16u(mv.y) << 16);
            unsigned p1 = bf16u(mv.z) | (bf16u(mv.w) << 16);
            mlds[mt][l][0] = p0; mlds[mt][l][1] = p1;
        }
    }
    __syncthreads();

    const float cap = capacity[b*G_ + gg];
    const float* WqL = Wq + E_*E_;
    const bool isN12 = (qq < 2);               // tile 12: rows m=192..199 are nodes iff qq<2
    const s16x4 z4 = {0, 0, 0, 0};

    #pragma unroll 1
    for (int hi2 = 0; hi2 < 2; ++hi2) {
        const int h = hg*2 + hi2;
        // ---- q B-fragment in-register ----
        s16x8 qBh, qBl;
        {
            float4 qb4 = *(const float4*)(qbase + b*E_ + h*16 + qq*4);
            float4 wl4 = *(const float4*)(WqL + h*16 + qq*4);
            float vv[4] = {qb4.x + cap*wl4.x, qb4.y + cap*wl4.y,
                           qb4.z + cap*wl4.z, qb4.w + cap*wl4.w};
            s16x4 hi4, lo4;
            #pragma unroll
            for (int j = 0; j < 4; ++j) { short hh = bfhi(vv[j]); hi4[j] = hh; lo4[j] = bflo(vv[j], hh); }
            qBh = cat8(hi4, z4); qBl = cat8(lo4, z4);
        }
        // ---- scoresT[m][g]: 19 independent MFMA tiles ----
        f32x4 sc[MT_];
        const size_t kb = (((size_t)(b*8 + h))*MT_)*256 + (size_t)l*4;
        #pragma unroll
        for (int mt = 0; mt < MT_; ++mt) {
            s16x8 Ah = cat8(*(const s16x4*)(kf_hi + kb + (size_t)mt*256), z4);
            s16x8 Al = cat8(*(const s16x4*)(kf_lo + kb + (size_t)mt*256), z4);
            f32x4 a = {0.f, 0.f, 0.f, 0.f};
            a = MFMA16(Ah, qBh, a);
            a = MFMA16(Ah, qBl, a);
            a = MFMA16(Al, qBh, a);
            sc[mt] = a;
        }
        // ---- scale + mask (from LDS) ----
        #pragma unroll
        for (int mt = 0; mt < MT_; ++mt) {
            const unsigned p0 = mlds[mt][l][0], p1 = mlds[mt][l][1];
            sc[mt][0] = sc[mt][0]*0.25f + bfbits(p0 & 0xffffu);
            sc[mt][1] = sc[mt][1]*0.25f + bfbits(p0 >> 16);
            sc[mt][2] = sc[mt][2]*0.25f + bfbits(p1 & 0xffffu);
            sc[mt][3] = sc[mt][3]*0.25f + bfbits(p1 >> 16);
        }
        // ---- segmented softmax, tree-reduced ----
        float mxN, mxS;
        {
            f32x4 a0 = max4(sc[0], sc[1]),  a1 = max4(sc[2], sc[3]),  a2 = max4(sc[4], sc[5]);
            f32x4 a3 = max4(sc[6], sc[7]),  a4 = max4(sc[8], sc[9]),  a5 = max4(sc[10], sc[11]);
            f32x4 mN4 = max4(max4(max4(a0, a1), max4(a2, a3)), max4(a4, a5));
            f32x4 s0 = max4(sc[13], sc[14]), s1 = max4(sc[15], sc[16]), s2 = max4(sc[17], sc[18]);
            f32x4 mS4 = max4(max4(s0, s1), s2);
            mxN = fmaxf(fmaxf(mN4[0], mN4[1]), fmaxf(mN4[2], mN4[3]));
            mxS = fmaxf(fmaxf(mS4[0], mS4[1]), fmaxf(mS4[2], mS4[3]));
            float t12 = fmaxf(fmaxf(sc[12][0], sc[12][1]), fmaxf(sc[12][2], sc[12][3]));
            if (isN12) mxN = fmaxf(mxN, t12); else mxS = fmaxf(mxS, t12);
            mxN = fmaxf(mxN, __shfl_xor(mxN, 16)); mxN = fmaxf(mxN, __shfl_xor(mxN, 32));
            mxS = fmaxf(mxS, __shfl_xor(mxS, 16)); mxS = fmaxf(mxS, __shfl_xor(mxS, 32));
        }
        float sN, sS;
        {
            f32x4 sA = {0.f,0.f,0.f,0.f}, sB = {0.f,0.f,0.f,0.f}, sC = {0.f,0.f,0.f,0.f};
            #pragma unroll
            for (int mt = 0; mt < 12; mt += 2) {
                f32x4 e0, e1;
                #pragma unroll
                for (int r = 0; r < 4; ++r) { e0[r] = __expf(sc[mt][r]   - mxN);
                                              e1[r] = __expf(sc[mt+1][r] - mxN); }
                sc[mt] = e0; sc[mt+1] = e1; sA += e0; sB += e1;
            }
            #pragma unroll
            for (int mt = 13; mt < MT_; ++mt) {
                f32x4 e;
                #pragma unroll
                for (int r = 0; r < 4; ++r) e[r] = __expf(sc[mt][r] - mxS);
                sc[mt] = e; sC += e;
            }
            const float mx12 = isN12 ? mxN : mxS;
            float s12 = 0.f;
            #pragma unroll
            for (int r = 0; r < 4; ++r) { float e = __expf(sc[12][r] - mx12); sc[12][r] = e; s12 += e; }
            f32x4 sAB = sA + sB;
            sN = (sAB[0] + sAB[1]) + (sAB[2] + sAB[3]) + (isN12 ? s12 : 0.f);
            sS = (sC[0] + sC[1]) + (sC[2] + sC[3]) + (isN12 ? 0.f : s12);
            sN += __shfl_xor(sN, 16); sN += __shfl_xor(sN, 32);
            sS += __shfl_xor(sS, 16); sS += __shfl_xor(sS, 32);
        }
        const float rN = 1.f / sN, rS = 1.f / sS;
        #pragma unroll
        for (int mt = 0; mt < 12; ++mt) sc[mt] *= rN;
        { const float r12 = isN12 ? rN : rS; sc[12] *= r12; }
        #pragma unroll
        for (int mt = 13; mt < MT_; ++mt) sc[mt] *= rS;

        // ---- PV: outT[k2][g] += V^T * P ; P regs are already B-fragments ----
        f32x4 oA = {0.f,0.f,0.f,0.f}, oB = {0.f,0.f,0.f,0.f};
        const size_t vb = (((size_t)(b*8 + h))*MT_)*256 + (size_t)l*4;
        #pragma unroll
        for (int t = 0; t < 10; ++t) {
            const int mA = 2*t, mB = 2*t + 1;
            s16x4 ph0, pl0, ph1, pl1;
            #pragma unroll
            for (int j = 0; j < 4; ++j) { short hh = bfhi(sc[mA][j]); ph0[j] = hh; pl0[j] = bflo(sc[mA][j], hh); }
            s16x4 vA_h = *(const s16x4*)(vf_hi + vb + (size_t)mA*256);
            s16x4 vA_l = *(const s16x4*)(vf_lo + vb + (size_t)mA*256);
            s16x4 vB_h = z4, vB_l = z4;
            if (t < 9) {
                #pragma unroll
                for (int j = 0; j < 4; ++j) { short hh = bfhi(sc[mB][j]); ph1[j] = hh; pl1[j] = bflo(sc[mB][j], hh); }
                vB_h = *(const s16x4*)(vf_hi + vb + (size_t)mB*256);
                vB_l = *(const s16x4*)(vf_lo + vb + (size_t)mB*256);
            } else { ph1 = z4; pl1 = z4; }
            s16x8 Ah = cat8(vA_h, vB_h), Al = cat8(vA_l, vB_l);
            s16x8 Bh = cat8(ph0, ph1),   Bl = cat8(pl0, pl1);
            if (t & 1) { oB = MFMA16(Ah, Bh, oB); oB = MFMA16(Ah, Bl, oB); oB = MFMA16(Al, Bh, oB); }
            else       { oA = MFMA16(Ah, Bh, oA); oA = MFMA16(Ah, Bl, oA); oA = MFMA16(Al, Bh, oA); }
        }
        f32x4 osum = oA + oB;
        *(f32x4*)(outws + (((size_t)(b*NT_ + gt))*8 + h)*256 + (size_t)l*4) = osum;
    }
}

// =================== attn2: Wc + final logits GEMM + tanh + mask + softmax ===================
__global__ __launch_bounds__(64, 4) void attn2_kernel(
    const float* __restrict__ ninf_mask,
    const short* __restrict__ sf_hi, const short* __restrict__ sf_lo,
    const short* __restrict__ wf_hi, const short* __restrict__ wf_lo,
    const float* __restrict__ bc_,
    const float* __restrict__ outws,
    float* __restrict__ out)
{
    int id = blockIdx.x;                       // 3328 = 8*416
    { const int xcd = id & 7, pos = id >> 3; id = xcd*416 + pos; }
    const int b = id / NT_, gt = id % NT_;
    const int l = threadIdx.x, qq = l >> 4, li = l & 15;
    const int g0 = gt*16;

    // ---- attention-out B-fragments (split on load) ----
    s16x8 BhO[4], BlO[4];
    #pragma unroll
    for (int u = 0; u < 4; ++u) {
        f32x4 a0 = *(const f32x4*)(outws + (((size_t)(b*NT_ + gt))*8 + 2*u)*256 + (size_t)l*4);
        f32x4 a1 = *(const f32x4*)(outws + (((size_t)(b*NT_ + gt))*8 + 2*u + 1)*256 + (size_t)l*4);
        #pragma unroll
        for (int j = 0; j < 4; ++j) {
            short h0 = bfhi(a0[j]); BhO[u][j]   = h0; BlO[u][j]   = bflo(a0[j], h0);
            short h1 = bfhi(a1[j]); BhO[u][4+j] = h1; BlO[u][4+j] = bflo(a1[j], h1);
        }
    }
    // ---- Wc GEMM -> mhT tiles; D-tiles (2u,2u+1) ARE lane-local B-frag halves ----
    s16x8 Bh2[4], Bl2[4];
    #pragma unroll
    for (int u = 0; u < 4; ++u) {
        f32x4 t01[2];
        #pragma unroll
        for (int half = 0; half < 2; ++half) {
            const int jt = 2*u + half;
            f32x4 acc = {0.f, 0.f, 0.f, 0.f};
            #pragma unroll
            for (int uu = 0; uu < 4; ++uu) {
                const int base = (((3*8 + jt)*8 + 2*uu)*64 + l)*4;
                s16x8 Ah = cat8(*(const s16x4*)(wf_hi + base), *(const s16x4*)(wf_hi + base + 256));
                s16x8 Al = cat8(*(const s16x4*)(wf_lo + base), *(const s16x4*)(wf_lo + base + 256));
                acc = MFMA16(Ah, BhO[uu], acc);
                acc = MFMA16(Ah, BlO[uu], acc);
                acc = MFMA16(Al, BhO[uu], acc);
            }
            float4 b4 = *(const float4*)(bc_ + jt*16 + qq*4);
            acc[0] += b4.x; acc[1] += b4.y; acc[2] += b4.z; acc[3] += b4.w;
            t01[half] = acc;
        }
        #pragma unroll
        for (int j = 0; j < 4; ++j) {
            short h0 = bfhi(t01[0][j]); Bh2[u][j]   = h0; Bl2[u][j]   = bflo(t01[0][j], h0);
            short h1 = bfhi(t01[1][j]); Bh2[u][4+j] = h1; Bl2[u][4+j] = bflo(t01[1][j], h1);
        }
    }
    // ---- final logits zT[n][g] over 13 n-tiles ----
    f32x4 z[NT_];
    #pragma unroll
    for (int nt = 0; nt < NT_; ++nt) {
        f32x4 acc = {0.f, 0.f, 0.f, 0.f};
        #pragma unroll
        for (int u = 0; u < 4; ++u) {
            const size_t base = (((size_t)(b*NT_ + nt))*8 + 2*u)*256 + (size_t)l*4;
            s16x8 Ah = cat8(*(const s16x4*)(sf_hi + base), *(const s16x4*)(sf_hi + base + 256));
            s16x8 Al = cat8(*(const s16x4*)(sf_lo + base), *(const s16x4*)(sf_lo + base + 256));
            acc = MFMA16(Ah, Bh2[u], acc);
            acc = MFMA16(Ah, Bl2[u], acc);
            acc = MFMA16(Al, Bh2[u], acc);
        }
        z[nt] = acc;
    }
    // ---- logits = 10*tanh(z/sqrt(E)) + ninf ----
    const float rE = 0.08838834764831845f;
    const int ggl = (g0 + li < G_) ? (g0 + li) : (G_ - 1);
    const float* nb = ninf_mask + ((size_t)b*G_ + ggl)*NODE_;
    #pragma unroll
    for (int nt = 0; nt < NT_; ++nt) {
        #pragma unroll
        for (int r = 0; r < 4; ++r) {
            const int n = nt*16 + qq*4 + r;
            float lg;
            if (nt < 12 || (qq*4 + r) < 8) {
                float a2 = z[nt][r] * rE;
                float ex = __expf(2.f * a2);
                float th = 1.f - 2.f / (ex + 1.f);
                lg = CLIP_*th + nb[n];
            } else lg = -3.0e38f;
            z[nt][r] = lg;
        }
    }
    // ---- row softmax over n ----
    float mx;
    {
        f32x4 m0 = max4(z[0], z[1]),  m1 = max4(z[2], z[3]),  m2 = max4(z[4], z[5]);
        f32x4 m3 = max4(z[6], z[7]),  m4 = max4(z[8], z[9]),  m5 = max4(z[10], z[11]);
        f32x4 mm = max4(max4(max4(m0, m1), max4(m2, m3)), max4(max4(m4, m5), z[12]));
        mx = fmaxf(fmaxf(mm[0], mm[1]), fmaxf(mm[2], mm[3]));
        mx = fmaxf(mx, __shfl_xor(mx, 16)); mx = fmaxf(mx, __shfl_xor(mx, 32));
    }
    float sm;
    {
        f32x4 sA = {0.f,0.f,0.f,0.f}, sB = {0.f,0.f,0.f,0.f};
        #pragma unroll
        for (int nt = 0; nt < 12; nt += 2) {
            f32x4 e0, e1;
            #pragma unroll
            for (int r = 0; r < 4; ++r) { e0[r] = __expf(z[nt][r]   - mx);
                                          e1[r] = __expf(z[nt+1][r] - mx); }
            z[nt] = e0; z[nt+1] = e1; sA += e0; sB += e1;
        }
        f32x4 e;
        #pragma unroll
        for (int r = 0; r < 4; ++r) e[r] = __expf(z[12][r] - mx);
        z[12] = e; sA += e;
        f32x4 sAB = sA + sB;
        sm = (sAB[0] + sAB[1]) + (sAB[2] + sAB[3]);
        sm += __shfl_xor(sm, 16); sm += __shfl_xor(sm, 32);
    }
    const float rs = 1.f / sm;

    // ---- transpose via LDS in 64-n chunks, coalesced stores ----
    __shared__ float tl[16*69];
    float* ob = out + (size_t)b*G_*NODE_;
    #pragma unroll
    for (int ch = 0; ch < 4; ++ch) {
        const int ntn = (ch < 3) ? 4 : 1;
        for (int k = 0; k < ntn; ++k) {
            const int nt = ch*4 + k;
            #pragma unroll
            for (int r = 0; r < 4; ++r)
                tl[li*69 + k*16 + qq*4 + r] = z[nt][r] * rs;
        }
        __syncthreads();
        const int n = ch*64 + l;
        const bool nok = (ch < 3) || (l < 8);
        #pragma unroll
        for (int gi = 0; gi < 16; ++gi) {
            const int g = g0 + gi;
            if (nok && g < G_) ob[(size_t)g*NODE_ + n] = tl[gi*69 + l];
        }
        __syncthreads();
    }
}

// =================== launch ===================
extern "C" void kernel_launch(void* const* d_in, const int* in_sizes, int n_in,
                              void* d_out, int out_size, void* d_ws, size_t ws_size,
                              hipStream_t stream) {
    (void)in_sizes; (void)n_in; (void)out_size; (void)ws_size;
    const float* graph = (const float*)d_in[0];
    const float* capacity = (const float*)d_in[1];
    const float* sols_mask = (const float*)d_in[2];
    const float* ninf_mask = (const float*)d_in[3];
    const float* enc = (const float*)d_in[4];
    const float* Wq  = (const float*)d_in[5];
    const float* Wk  = (const float*)d_in[6];
    const float* Wv  = (const float*)d_in[7];
    const float* Wc  = (const float*)d_in[8];
    const float* bc  = (const float*)d_in[9];
    const float* Wkl = (const float*)d_in[10];
    float* out = (float*)d_out;

    // ws layout (bytes), total 94,765,056 (same as round 2)
    char* wsb = (char*)d_ws;
    short* kf_hi = (short*)(wsb);
    short* kf_lo = (short*)(wsb + 19922944);
    short* sf_hi = (short*)(wsb + 39845888);
    short* sf_lo = (short*)(wsb + 53477376);
    float* outws = (float*)(wsb + 67108864);   // B*NT*8*256 f32 = 27,262,976 B
    short* wf_hi = (short*)(wsb + 94371840);
    short* wf_lo = (short*)(wsb + 94502912);
    float* qb    = (float*)(wsb + 94633984);
    // v fragments live in d_out (dead before attn2 overwrites it)
    short* vf_hi = (short*)d_out;
    short* vf_lo = (short*)d_out + 9961472;

    wfrag_kernel<<<dim3(4, 8), 64, 0, stream>>>(Wk, Wv, Wkl, Wc, wf_hi, wf_lo);
    qbase_kernel<<<B_, 128, 0, stream>>>(graph, Wq, qb);
    proj_kernel<<<MT_*B_, 64, 0, stream>>>(enc, wf_hi, wf_lo, kf_hi, kf_lo, vf_hi, vf_lo, sf_hi, sf_lo);
    attn1_kernel<<<NT_*B_*4, 64, 0, stream>>>(capacity, sols_mask, ninf_mask, Wq, qb,
                                              kf_hi, kf_lo, vf_hi, vf_lo, outws);
    attn2_kernel<<<NT_*B_, 64, 0, stream>>>(ninf_mask, sf_hi, sf_lo, wf_hi, wf_lo, bc, outws, out);
}

// Round 4
// 190.499 us; speedup vs baseline: 9.5625x; 2.3183x over previous
//
#include <hip/hip_runtime.h>

#define B_    256
#define G_    200
#define S_    100
#define NODE_ 200
#define E_    128
#define H_    8
#define M_    300
#define MT_   19     // m tiles of 16 (304 padded)
#define NT_   13     // n/g tiles of 16 (208 padded)
#define CLIP_ 10.0f

typedef float    f32x4 __attribute__((ext_vector_type(4)));
typedef short    s16x4 __attribute__((ext_vector_type(4)));
typedef short    s16x8 __attribute__((ext_vector_type(8)));
typedef unsigned u32x4 __attribute__((ext_vector_type(4)));

#define MFMA16(A, B, C) __builtin_amdgcn_mfma_f32_16x16x32_bf16(A, B, C, 0, 0, 0)

// ---- split-bf16 helpers: x ~= hi + lo ----
__device__ __forceinline__ unsigned bf16u(float x) {
    unsigned u = __builtin_bit_cast(unsigned, x);
    return (u + 0x7fffu + ((u >> 16) & 1u)) >> 16;
}
__device__ __forceinline__ float bfbits(unsigned hb16) {
    return __builtin_bit_cast(float, hb16 << 16);
}
__device__ __forceinline__ short bfhi(float x) { return (short)bf16u(x); }
__device__ __forceinline__ short bflo(float x, short hi) {
    float hf = __builtin_bit_cast(float, ((unsigned)(unsigned short)hi) << 16);
    return (short)bf16u(x - hf);
}
// HW packed convert: dst.lo16 = bf16(a), dst.hi16 = bf16(b)
__device__ __forceinline__ unsigned cvtpk(float a, float b) {
    unsigned r;
    asm("v_cvt_pk_bf16_f32 %0, %1, %2" : "=v"(r) : "v"(a), "v"(b));
    return r;
}
__device__ __forceinline__ s16x8 cat8(s16x4 a, s16x4 b) {
    s16x8 r; r[0]=a[0]; r[1]=a[1]; r[2]=a[2]; r[3]=a[3];
             r[4]=b[0]; r[5]=b[1]; r[6]=b[2]; r[7]=b[3]; return r;
}
__device__ __forceinline__ f32x4 max4(f32x4 a, f32x4 b) {
    f32x4 r; r[0]=fmaxf(a[0],b[0]); r[1]=fmaxf(a[1],b[1]);
             r[2]=fmaxf(a[2],b[2]); r[3]=fmaxf(a[3],b[3]); return r;
}
// pack f32x4 -> two interleaved B-fragments {hi,lo} and {lo,hi}
__device__ __forceinline__ void split_pack(f32x4 v, s16x8& B1, s16x8& B2) {
    unsigned h01 = cvtpk(v[0], v[1]);
    unsigned h23 = cvtpk(v[2], v[3]);
    float e0 = v[0] - __builtin_bit_cast(float, h01 << 16);
    float e1 = v[1] - __builtin_bit_cast(float, h01 & 0xffff0000u);
    float e2 = v[2] - __builtin_bit_cast(float, h23 << 16);
    float e3 = v[3] - __builtin_bit_cast(float, h23 & 0xffff0000u);
    unsigned l01 = cvtpk(e0, e1), l23 = cvtpk(e2, e3);
    u32x4 w1 = {h01, h23, l01, l23};
    u32x4 w2 = {l01, l23, h01, h23};
    B1 = __builtin_bit_cast(s16x8, w1);
    B2 = __builtin_bit_cast(s16x8, w2);
}

// =================== setup: W fragments (s16x8-grain, hi/lo separate) ===================
// wf8_*[((p*8+ct)*4+u)*512 + l*8 + {0..7}]: slots0-3 = kc=2u, slots4-7 = kc=2u+1
__global__ __launch_bounds__(64) void wfrag_kernel(
    const float* __restrict__ Wk, const float* __restrict__ Wv,
    const float* __restrict__ Wl, const float* __restrict__ Wc,
    short* __restrict__ wf8_hi, short* __restrict__ wf8_lo)
{
    const int p = blockIdx.x, ct = blockIdx.y;
    const int l = threadIdx.x, qq = l >> 4, li = l & 15;
    const float* W = (p == 0) ? Wk : ((p == 1) ? Wv : ((p == 2) ? Wl : Wc));
    for (int kc = 0; kc < 8; ++kc) {
        s16x4 hi, lo;
        #pragma unroll
        for (int j = 0; j < 4; ++j) {
            float v = W[(kc*16 + qq*4 + j)*E_ + ct*16 + li];
            short h = bfhi(v); hi[j] = h; lo[j] = bflo(v, h);
        }
        const int ix = (((p*8 + ct)*4 + (kc >> 1))*64 + l)*8 + (kc & 1)*4;
        *(s16x4*)(wf8_hi + ix) = hi;
        *(s16x4*)(wf8_lo + ix) = lo;
    }
}

// =================== qbase[b][c] = graph[b] @ Wq[:128] ===================
__global__ __launch_bounds__(128) void qbase_kernel(
    const float* __restrict__ graph, const float* __restrict__ Wq,
    float* __restrict__ qbase)
{
    const int b = blockIdx.x, c = threadIdx.x;
    __shared__ float gs[E_];
    gs[c] = graph[b*E_ + c];
    __syncthreads();
    float acc = 0.f;
    #pragma unroll 8
    for (int e = 0; e < E_; ++e) acc += gs[e] * Wq[e*E_ + c];
    qbase[b*E_ + c] = acc;
}

// =================== proj: k/v/shk fragments ===================
// kf_il/vf_il: [((b*8+h)*19+mt)*512 + l*8] = {hi4, lo4}  (b128 units)
// sf8_*:       [((b*13+nt)*4+u)*512 + l*8] slots0-3=ct2u, 4-7=ct2u+1
__global__ __launch_bounds__(64, 4) void proj_kernel(
    const float* __restrict__ enc,
    const short* __restrict__ wf8_hi, const short* __restrict__ wf8_lo,
    short* __restrict__ kf_il, short* __restrict__ vf_il,
    short* __restrict__ sf8_hi, short* __restrict__ sf8_lo)
{
    int id = blockIdx.x;                       // 4864 = 8*608: XCD-chunked swizzle
    { const int xcd = id & 7, pos = id >> 3; id = xcd*608 + pos; }
    const int b = id / MT_, mt = id % MT_;
    const int l = threadIdx.x, qq = l >> 4, li = l & 15;
    const int m = mt*16 + li;

    s16x8 Ahi[4], Alo[4];
    #pragma unroll
    for (int u = 0; u < 4; ++u) {
        float va[8];
        if (m < M_) {
            const float* ep = enc + ((size_t)b*M_ + m)*E_ + u*32 + qq*4;
            float4 f0 = *(const float4*)ep;
            float4 f1 = *(const float4*)(ep + 16);
            va[0]=f0.x; va[1]=f0.y; va[2]=f0.z; va[3]=f0.w;
            va[4]=f1.x; va[5]=f1.y; va[6]=f1.z; va[7]=f1.w;
        } else {
            #pragma unroll
            for (int j = 0; j < 8; ++j) va[j] = 0.f;
        }
        #pragma unroll
        for (int j = 0; j < 8; ++j) {
            short h = bfhi(va[j]); Ahi[u][j] = h; Alo[u][j] = bflo(va[j], h);
        }
    }

    __shared__ unsigned tile[16*17];

    #pragma unroll
    for (int p = 0; p < 3; ++p) {
        if (p == 2 && mt >= NT_) break;
        #pragma unroll
        for (int ct = 0; ct < 8; ++ct) {
            f32x4 acc = {0.f, 0.f, 0.f, 0.f};
            #pragma unroll
            for (int u = 0; u < 4; ++u) {
                const int base = (((p*8 + ct)*4 + u)*64 + l)*8;
                s16x8 Bh = *(const s16x8*)(wf8_hi + base);
                s16x8 Bl = *(const s16x8*)(wf8_lo + base);
                acc = MFMA16(Ahi[u], Bh, acc);
                acc = MFMA16(Ahi[u], Bl, acc);
                acc = MFMA16(Alo[u], Bh, acc);
            }
            if (p == 1) {                       // v: D-layout is the PV A-frag
                s16x4 oh, ol;
                #pragma unroll
                for (int r = 0; r < 4; ++r) { short h = bfhi(acc[r]); oh[r] = h; ol[r] = bflo(acc[r], h); }
                const size_t ix = (((size_t)(b*8 + ct))*MT_ + mt)*512 + (size_t)l*8;
                *(s16x8*)(vf_il + ix) = cat8(oh, ol);
            } else {                            // k / shk: transpose via LDS bounce
                #pragma unroll
                for (int r = 0; r < 4; ++r) {
                    short h = bfhi(acc[r]); short lo = bflo(acc[r], h);
                    tile[(qq*4 + r)*17 + li] = (((unsigned)(unsigned short)h) << 16) | (unsigned short)(unsigned)lo;
                }
                __syncthreads();
                s16x4 oh, ol;
                #pragma unroll
                for (int j = 0; j < 4; ++j) {
                    unsigned wv = tile[li*17 + qq*4 + j];
                    oh[j] = (short)(wv >> 16); ol[j] = (short)(wv & 0xffffu);
                }
                if (p == 0) {
                    const size_t ix = (((size_t)(b*8 + ct))*MT_ + mt)*512 + (size_t)l*8;
                    *(s16x8*)(kf_il + ix) = cat8(oh, ol);
                } else {
                    const size_t ix = (((size_t)(b*NT_ + mt))*4 + (ct >> 1))*512 + (size_t)l*8 + (ct & 1)*4;
                    *(s16x4*)(sf8_hi + ix) = oh;
                    *(s16x4*)(sf8_lo + ix) = ol;
                }
                __syncthreads();
            }
        }
    }
}

// =================== attn1: scores+softmax+PV, 4 waves x 2 heads ===================
__global__ __launch_bounds__(256, 3) void attn1_kernel(
    const float* __restrict__ capacity, const float* __restrict__ sols_mask,
    const float* __restrict__ ninf_mask, const float* __restrict__ Wq,
    const float* __restrict__ qbase,
    const short* __restrict__ kf_il, const short* __restrict__ vf_il,
    float* __restrict__ outws)
{
    int id = blockIdx.x;                       // 3328 = 8*416
    { const int xcd = id & 7, pos = id >> 3; id = xcd*416 + pos; }
    const int b = id / NT_, gt = id % NT_;
    const int t = threadIdx.x;
    const int w = t >> 6, l = t & 63, qq = l >> 4, li = l & 15;
    const int g0 = gt*16;

    __shared__ unsigned mlds[MT_][64][2];      // 9728 B, bf16-packed masks

    // ---- coalesced mask fill: masks for rows g0..g0+15 are contiguous ----
    {
        const size_t bg = (size_t)b*G_;
        for (int f = t; f < 1600; f += 256) {          // ninf: 16 rows x 100 float2
            const int g = f/100, p = f - g*100;
            int gg = g0 + g; gg = (gg < G_) ? gg : G_-1;
            float2 v = *(const float2*)(ninf_mask + (bg + gg)*NODE_ + p*2);
            const int mm = p*2;
            mlds[mm>>4][((mm>>2)&3)*16 + g][(mm>>1)&1] = cvtpk(v.x, v.y);
        }
        for (int f = t; f < 800; f += 256) {           // sols: 16 rows x 50 float2
            const int g = f/50, p = f - g*50;
            int gg = g0 + g; gg = (gg < G_) ? gg : G_-1;
            float2 v = *(const float2*)(sols_mask + (bg + gg)*S_ + p*2);
            const int mm = 200 + p*2;
            mlds[mm>>4][((mm>>2)&3)*16 + g][(mm>>1)&1] = cvtpk(v.x, v.y);
        }
        if (t < 32) {                                  // pad rows m=300..303
            const unsigned nu = bf16u(-3.0e38f);
            mlds[18][48 + (t>>1)][t&1] = nu | (nu << 16);
        }
    }
    __syncthreads();

    int ggl = g0 + li; ggl = (ggl < G_) ? ggl : G_-1;
    const float cap = capacity[b*G_ + ggl];
    const bool isN12 = (qq < 2);               // tile 12 rows m=192..199 are nodes iff qq<2

    #pragma unroll 1
    for (int hi2 = 0; hi2 < 2; ++hi2) {
        const int h = w*2 + hi2;
        // ---- q interleaved B-frags ----
        s16x8 qB1, qB2;
        {
            float4 qb4 = *(const float4*)(qbase + b*E_ + h*16 + qq*4);
            float4 wl4 = *(const float4*)(Wq + E_*E_ + h*16 + qq*4);
            f32x4 qv = {qb4.x + cap*wl4.x, qb4.y + cap*wl4.y,
                        qb4.z + cap*wl4.z, qb4.w + cap*wl4.w};
            split_pack(qv, qB1, qB2);
        }
        // ---- scoresT[m][g]: one b128 load + 2 MFMA per tile ----
        f32x4 sc[MT_];
        const size_t kb = ((size_t)(b*8 + h)*MT_)*512 + (size_t)l*8;
        #pragma unroll
        for (int mt = 0; mt < MT_; ++mt) {
            s16x8 kf8 = *(const s16x8*)(kf_il + kb + (size_t)mt*512);
            f32x4 a = {0.f, 0.f, 0.f, 0.f};
            a = MFMA16(kf8, qB1, a);
            a = MFMA16(kf8, qB2, a);
            sc[mt] = a;
        }
        // ---- scale + mask ----
        #pragma unroll
        for (int mt = 0; mt < MT_; ++mt) {
            uint2 mp = *(const uint2*)&mlds[mt][l][0];
            sc[mt][0] = sc[mt][0]*0.25f + bfbits(mp.x & 0xffffu);
            sc[mt][1] = sc[mt][1]*0.25f + bfbits(mp.x >> 16);
            sc[mt][2] = sc[mt][2]*0.25f + bfbits(mp.y & 0xffffu);
            sc[mt][3] = sc[mt][3]*0.25f + bfbits(mp.y >> 16);
        }
        // ---- segmented softmax ----
        float mxN, mxS;
        {
            f32x4 a0 = max4(sc[0], sc[1]),  a1 = max4(sc[2], sc[3]),  a2 = max4(sc[4], sc[5]);
            f32x4 a3 = max4(sc[6], sc[7]),  a4 = max4(sc[8], sc[9]),  a5 = max4(sc[10], sc[11]);
            f32x4 mN4 = max4(max4(max4(a0, a1), max4(a2, a3)), max4(a4, a5));
            f32x4 s0 = max4(sc[13], sc[14]), s1 = max4(sc[15], sc[16]), s2 = max4(sc[17], sc[18]);
            f32x4 mS4 = max4(max4(s0, s1), s2);
            mxN = fmaxf(fmaxf(mN4[0], mN4[1]), fmaxf(mN4[2], mN4[3]));
            mxS = fmaxf(fmaxf(mS4[0], mS4[1]), fmaxf(mS4[2], mS4[3]));
            float t12 = fmaxf(fmaxf(sc[12][0], sc[12][1]), fmaxf(sc[12][2], sc[12][3]));
            if (isN12) mxN = fmaxf(mxN, t12); else mxS = fmaxf(mxS, t12);
            mxN = fmaxf(mxN, __shfl_xor(mxN, 16)); mxN = fmaxf(mxN, __shfl_xor(mxN, 32));
            mxS = fmaxf(mxS, __shfl_xor(mxS, 16)); mxS = fmaxf(mxS, __shfl_xor(mxS, 32));
        }
        float sN, sS;
        {
            f32x4 sA = {0.f,0.f,0.f,0.f}, sB = {0.f,0.f,0.f,0.f}, sC = {0.f,0.f,0.f,0.f};
            #pragma unroll
            for (int mt = 0; mt < 12; mt += 2) {
                f32x4 e0, e1;
                #pragma unroll
                for (int r = 0; r < 4; ++r) { e0[r] = __expf(sc[mt][r]   - mxN);
                                              e1[r] = __expf(sc[mt+1][r] - mxN); }
                sc[mt] = e0; sc[mt+1] = e1; sA += e0; sB += e1;
            }
            #pragma unroll
            for (int mt = 13; mt < MT_; ++mt) {
                f32x4 e;
                #pragma unroll
                for (int r = 0; r < 4; ++r) e[r] = __expf(sc[mt][r] - mxS);
                sc[mt] = e; sC += e;
            }
            const float mx12 = isN12 ? mxN : mxS;
            float s12 = 0.f;
            #pragma unroll
            for (int r = 0; r < 4; ++r) { float e = __expf(sc[12][r] - mx12); sc[12][r] = e; s12 += e; }
            f32x4 sAB = sA + sB;
            sN = (sAB[0] + sAB[1]) + (sAB[2] + sAB[3]) + (isN12 ? s12 : 0.f);
            sS = (sC[0] + sC[1]) + (sC[2] + sC[3]) + (isN12 ? 0.f : s12);
            sN += __shfl_xor(sN, 16); sN += __shfl_xor(sN, 32);
            sS += __shfl_xor(sS, 16); sS += __shfl_xor(sS, 32);
        }
        const float rN = 1.f / sN, rS = 1.f / sS;
        #pragma unroll
        for (int mt = 0; mt < 12; ++mt) sc[mt] *= rN;
        { const float r12 = isN12 ? rN : rS; sc[12] *= r12; }
        #pragma unroll
        for (int mt = 13; mt < MT_; ++mt) sc[mt] *= rS;

        // ---- PV: one b128 V load + 2 MFMA per tile, 4 rotating accumulators ----
        f32x4 oacc[4] = {{0.f,0.f,0.f,0.f},{0.f,0.f,0.f,0.f},
                         {0.f,0.f,0.f,0.f},{0.f,0.f,0.f,0.f}};
        #pragma unroll
        for (int mt = 0; mt < MT_; ++mt) {
            s16x8 pB1, pB2;
            split_pack(sc[mt], pB1, pB2);
            s16x8 vf8 = *(const s16x8*)(vf_il + kb + (size_t)mt*512);
            oacc[mt & 3] = MFMA16(vf8, pB1, oacc[mt & 3]);
            oacc[mt & 3] = MFMA16(vf8, pB2, oacc[mt & 3]);
        }
        f32x4 osum = (oacc[0] + oacc[1]) + (oacc[2] + oacc[3]);
        *(f32x4*)(outws + (((size_t)(b*NT_ + gt))*8 + h)*256 + (size_t)l*4) = osum;
    }
}

// =================== attn2: Wc + final logits GEMM + tanh + mask + softmax ===================
__global__ __launch_bounds__(64, 4) void attn2_kernel(
    const float* __restrict__ ninf_mask,
    const short* __restrict__ sf8_hi, const short* __restrict__ sf8_lo,
    const short* __restrict__ wf8_hi, const short* __restrict__ wf8_lo,
    const float* __restrict__ bc_,
    const float* __restrict__ outws,
    float* __restrict__ out)
{
    int id = blockIdx.x;                       // 3328 = 8*416
    { const int xcd = id & 7, pos = id >> 3; id = xcd*416 + pos; }
    const int b = id / NT_, gt = id % NT_;
    const int l = threadIdx.x, qq = l >> 4, li = l & 15;
    const int g0 = gt*16;

    __shared__ float pool[16*308];             // masks; reused as transpose buffer

    // ---- coalesced ninf staging (rows g0..g0+15, clamped) ----
    {
        const size_t bg = (size_t)b*G_;
        for (int f = l; f < 800; f += 64) {
            const int g = f/50, p = f - g*50;
            int gg = g0 + g; gg = (gg < G_) ? gg : G_-1;
            *(float4*)&pool[g*308 + p*4] = *(const float4*)(ninf_mask + (bg + gg)*NODE_ + p*4);
        }
    }
    __syncthreads();

    // ---- attention-out B-fragments (split on load) ----
    s16x8 BhO[4], BlO[4];
    #pragma unroll
    for (int u = 0; u < 4; ++u) {
        f32x4 a0 = *(const f32x4*)(outws + (((size_t)(b*NT_ + gt))*8 + 2*u)*256 + (size_t)l*4);
        f32x4 a1 = *(const f32x4*)(outws + (((size_t)(b*NT_ + gt))*8 + 2*u + 1)*256 + (size_t)l*4);
        unsigned ha = cvtpk(a0[0], a0[1]), hb = cvtpk(a0[2], a0[3]);
        unsigned hc = cvtpk(a1[0], a1[1]), hd = cvtpk(a1[2], a1[3]);
        float e0 = a0[0] - __builtin_bit_cast(float, ha << 16);
        float e1 = a0[1] - __builtin_bit_cast(float, ha & 0xffff0000u);
        float e2 = a0[2] - __builtin_bit_cast(float, hb << 16);
        float e3 = a0[3] - __builtin_bit_cast(float, hb & 0xffff0000u);
        float e4 = a1[0] - __builtin_bit_cast(float, hc << 16);
        float e5 = a1[1] - __builtin_bit_cast(float, hc & 0xffff0000u);
        float e6 = a1[2] - __builtin_bit_cast(float, hd << 16);
        float e7 = a1[3] - __builtin_bit_cast(float, hd & 0xffff0000u);
        unsigned la = cvtpk(e0, e1), lb = cvtpk(e2, e3);
        unsigned lc = cvtpk(e4, e5), ld = cvtpk(e6, e7);
        u32x4 wh = {ha, hb, hc, hd}, wl = {la, lb, lc, ld};
        BhO[u] = __builtin_bit_cast(s16x8, wh);
        BlO[u] = __builtin_bit_cast(s16x8, wl);
    }
    // ---- Wc GEMM -> mh B-fragments ----
    s16x8 Bh2[4], Bl2[4];
    #pragma unroll
    for (int u = 0; u < 4; ++u) {
        f32x4 t01[2];
        #pragma unroll
        for (int half = 0; half < 2; ++half) {
            const int jt = 2*u + half;
            f32x4 acc = {0.f, 0.f, 0.f, 0.f};
            #pragma unroll
            for (int uu = 0; uu < 4; ++uu) {
                const int base = (((3*8 + jt)*4 + uu)*64 + l)*8;
                s16x8 Ah = *(const s16x8*)(wf8_hi + base);
                s16x8 Al = *(const s16x8*)(wf8_lo + base);
                acc = MFMA16(Ah, BhO[uu], acc);
                acc = MFMA16(Ah, BlO[uu], acc);
                acc = MFMA16(Al, BhO[uu], acc);
            }
            float4 b4 = *(const float4*)(bc_ + jt*16 + qq*4);
            acc[0] += b4.x; acc[1] += b4.y; acc[2] += b4.z; acc[3] += b4.w;
            t01[half] = acc;
        }
        unsigned h0 = cvtpk(t01[0][0], t01[0][1]), h1 = cvtpk(t01[0][2], t01[0][3]);
        unsigned h2 = cvtpk(t01[1][0], t01[1][1]), h3 = cvtpk(t01[1][2], t01[1][3]);
        float e0 = t01[0][0] - __builtin_bit_cast(float, h0 << 16);
        float e1 = t01[0][1] - __builtin_bit_cast(float, h0 & 0xffff0000u);
        float e2 = t01[0][2] - __builtin_bit_cast(float, h1 << 16);
        float e3 = t01[0][3] - __builtin_bit_cast(float, h1 & 0xffff0000u);
        float e4 = t01[1][0] - __builtin_bit_cast(float, h2 << 16);
        float e5 = t01[1][1] - __builtin_bit_cast(float, h2 & 0xffff0000u);
        float e6 = t01[1][2] - __builtin_bit_cast(float, h3 << 16);
        float e7 = t01[1][3] - __builtin_bit_cast(float, h3 & 0xffff0000u);
        unsigned l0 = cvtpk(e0, e1), l1 = cvtpk(e2, e3);
        unsigned l2 = cvtpk(e4, e5), l3 = cvtpk(e6, e7);
        u32x4 wh = {h0, h1, h2, h3}, wl = {l0, l1, l2, l3};
        Bh2[u] = __builtin_bit_cast(s16x8, wh);
        Bl2[u] = __builtin_bit_cast(s16x8, wl);
    }
    // ---- final logits zT[n][g] ----
    f32x4 z[NT_];
    #pragma unroll
    for (int nt = 0; nt < NT_; ++nt) {
        f32x4 acc = {0.f, 0.f, 0.f, 0.f};
        #pragma unroll
        for (int u = 0; u < 4; ++u) {
            const size_t base = (((size_t)(b*NT_ + nt))*4 + u)*512 + (size_t)l*8;
            s16x8 Ah = *(const s16x8*)(sf8_hi + base);
            s16x8 Al = *(const s16x8*)(sf8_lo + base);
            acc = MFMA16(Ah, Bh2[u], acc);
            acc = MFMA16(Ah, Bl2[u], acc);
            acc = MFMA16(Al, Bh2[u], acc);
        }
        z[nt] = acc;
    }
    // ---- logits = 10*tanh(z/sqrt(E)) + ninf (mask from LDS) ----
    const float rE = 0.08838834764831845f;
    #pragma unroll
    for (int nt = 0; nt < NT_; ++nt) {
        f32x4 mk = *(const f32x4*)&pool[li*308 + nt*16 + qq*4];
        #pragma unroll
        for (int r = 0; r < 4; ++r) {
            float lg;
            if (nt < 12 || (qq*4 + r) < 8) {
                float a2 = z[nt][r] * rE;
                float ex = __expf(2.f * a2);
                float th = 1.f - 2.f / (ex + 1.f);
                lg = CLIP_*th + mk[r];
            } else lg = -3.0e38f;
            z[nt][r] = lg;
        }
    }
    // ---- row softmax over n ----
    float mx;
    {
        f32x4 m0 = max4(z[0], z[1]),  m1 = max4(z[2], z[3]),  m2 = max4(z[4], z[5]);
        f32x4 m3 = max4(z[6], z[7]),  m4 = max4(z[8], z[9]),  m5 = max4(z[10], z[11]);
        f32x4 mm = max4(max4(max4(m0, m1), max4(m2, m3)), max4(max4(m4, m5), z[12]));
        mx = fmaxf(fmaxf(mm[0], mm[1]), fmaxf(mm[2], mm[3]));
        mx = fmaxf(mx, __shfl_xor(mx, 16)); mx = fmaxf(mx, __shfl_xor(mx, 32));
    }
    float sm;
    {
        f32x4 sA = {0.f,0.f,0.f,0.f}, sB = {0.f,0.f,0.f,0.f};
        #pragma unroll
        for (int nt = 0; nt < 12; nt += 2) {
            f32x4 e0, e1;
            #pragma unroll
            for (int r = 0; r < 4; ++r) { e0[r] = __expf(z[nt][r]   - mx);
                                          e1[r] = __expf(z[nt+1][r] - mx); }
            z[nt] = e0; z[nt+1] = e1; sA += e0; sB += e1;
        }
        f32x4 e;
        #pragma unroll
        for (int r = 0; r < 4; ++r) e[r] = __expf(z[12][r] - mx);
        z[12] = e; sA += e;
        f32x4 sAB = sA + sB;
        sm = (sAB[0] + sAB[1]) + (sAB[2] + sAB[3]);
        sm += __shfl_xor(sm, 16); sm += __shfl_xor(sm, 32);
    }
    const float rs = 1.f / sm;

    // ---- transpose via LDS (pool reused, stride 69), coalesced stores ----
    float* ob = out + (size_t)b*G_*NODE_;
    __syncthreads();
    #pragma unroll
    for (int ch = 0; ch < 4; ++ch) {
        const int ntn = (ch < 3) ? 4 : 1;
        for (int k = 0; k < ntn; ++k) {
            const int nt = ch*4 + k;
            #pragma unroll
            for (int r = 0; r < 4; ++r)
                pool[li*69 + k*16 + qq*4 + r] = z[nt][r] * rs;
        }
        __syncthreads();
        const int n = ch*64 + l;
        const bool nok = (ch < 3) || (l < 8);
        #pragma unroll
        for (int gi = 0; gi < 16; ++gi) {
            const int g = g0 + gi;
            if (nok && g < G_) ob[(size_t)g*NODE_ + n] = pool[gi*69 + l];
        }
        __syncthreads();
    }
}

// =================== launch ===================
extern "C" void kernel_launch(void* const* d_in, const int* in_sizes, int n_in,
                              void* d_out, int out_size, void* d_ws, size_t ws_size,
                              hipStream_t stream) {
    (void)in_sizes; (void)n_in; (void)out_size; (void)ws_size;
    const float* graph = (const float*)d_in[0];
    const float* capacity = (const float*)d_in[1];
    const float* sols_mask = (const float*)d_in[2];
    const float* ninf_mask = (const float*)d_in[3];
    const float* enc = (const float*)d_in[4];
    const float* Wq  = (const float*)d_in[5];
    const float* Wk  = (const float*)d_in[6];
    const float* Wv  = (const float*)d_in[7];
    const float* Wc  = (const float*)d_in[8];
    const float* bc  = (const float*)d_in[9];
    const float* Wkl = (const float*)d_in[10];
    float* out = (float*)d_out;

    // ws layout (bytes), total 94,765,056 (proven size)
    char* wsb = (char*)d_ws;
    short* kf_il  = (short*)(wsb);                   // 39,845,888
    short* sf8_hi = (short*)(wsb + 39845888);        // 13,631,488
    short* sf8_lo = (short*)(wsb + 53477376);        // 13,631,488
    short* wf8_hi = (short*)(wsb + 67108864);        //    131,072
    short* wf8_lo = (short*)(wsb + 67239936);        //    131,072
    float* qb     = (float*)(wsb + 67371008);        //    131,072
    float* outws  = (float*)(wsb + 67502080);        // 27,262,976 -> 94,765,056
    // v fragments live in d_out (dead before attn2 overwrites it): 39.8MB <= 40.96MB
    short* vf_il  = (short*)d_out;

    wfrag_kernel<<<dim3(4, 8), 64, 0, stream>>>(Wk, Wv, Wkl, Wc, wf8_hi, wf8_lo);
    qbase_kernel<<<B_, 128, 0, stream>>>(graph, Wq, qb);
    proj_kernel<<<MT_*B_, 64, 0, stream>>>(enc, wf8_hi, wf8_lo, kf_il, vf_il, sf8_hi, sf8_lo);
    attn1_kernel<<<NT_*B_, 256, 0, stream>>>(capacity, sols_mask, ninf_mask, Wq, qb,
                                             kf_il, vf_il, outws);
    attn2_kernel<<<NT_*B_, 64, 0, stream>>>(ninf_mask, sf8_hi, sf8_lo, wf8_hi, wf8_lo,
                                            bc, outws, out);
}